// Round 1
// baseline (214.613 us; speedup 1.0000x reference)
//
#include <hip/hip_runtime.h>
#include <math.h>

// Problem dims
#define NB 64
#define NA 23
#define NT 128
#define ND 256
#define NAE 32
#define NS 6
#define NH 8
#define NDM 288

// Workspace layout (float offsets)
#define OFF_PET    0                 // peT[e][t] : 256*128
#define OFF_PECUM  32768             // PEcum[L][e] : 129*256 (rows 1..128 used)
#define OFF_CNT    32768             // PEcum row 0 unused (L>=1) -> completion counter (int)
#define OFF_WKT    65792             // WkT[j][e<256] = Wk[e][j]/sqrt(32) : 256*256
#define OFF_VWO    131328            // VWo[h][e] : 8*288
#define OFF_CST    133632            // [0..5]=sWf, [6]=b_static.Wg1+bg, [7]=bo.Wg0, [8..15]=vb[h]
#define OFF_S      133648            // s[b][a] : 1472
// total floats = 135120 (540,480 bytes of ws)

// Parallel setup: 393 blocks.
//  blocks [0,128)   : pe table + prefix scan, 2 e-columns per block
//  blocks [128,384) : WkT transpose, one j-row per block
//  blocks [384,392) : per-head VWo (+ redundant WoWg slice) + cst[8+h]
//  block  392       : cst[0..7] + completion-counter reset
__global__ __launch_bounds__(256) void setup_kernel(
    const float* __restrict__ Wk, const float* __restrict__ Wv,
    const float* __restrict__ Wo, const float* __restrict__ Wg,
    const float* __restrict__ bv, const float* __restrict__ bo,
    const float* __restrict__ W_static, const float* __restrict__ b_static,
    const float* __restrict__ bg, float* __restrict__ ws)
{
    const int blk = blockIdx.x;
    const int tid = threadIdx.x;
    float* peT   = ws + OFF_PET;
    float* PEcum = ws + OFF_PECUM;
    float* WkT   = ws + OFF_WKT;
    float* VWo   = ws + OFF_VWO;
    float* cst   = ws + OFF_CST;

    if (blk < 128) {
        // pe: e = blk*2 + (tid>>7), t = tid&127. One transcendental per thread.
        const int g = tid >> 7, t = tid & 127;
        const int e = blk * 2 + g;
        const int i = e >> 1;
        const float kdiv = 0.07195578415606394f; // ln(10000)/128
        const float dv = expf(-(float)i * kdiv);
        const float ang = (float)t * dv;
        const float v = (e & 1) ? cosf(ang) : sinf(ang);
        peT[e * NT + t] = v;
        __shared__ float buf[256];
        buf[tid] = v;
        // inclusive Hillis-Steele scan over t within each 128-group
        #pragma unroll
        for (int s = 1; s < 128; s <<= 1) {
            __syncthreads();
            float add = (t >= s) ? buf[tid - s] : 0.f;
            __syncthreads();
            buf[tid] += add;
        }
        __syncthreads();
        PEcum[(t + 1) * ND + e] = buf[tid];
    } else if (blk < 384) {
        // WkT[j][e] = Wk[e][j] * 1/sqrt(32), e<256 only (E_var cols cancel in softmax)
        const int j = blk - 128;
        const float scale = 0.17677669529663687f;
        WkT[j * 256 + tid] = Wk[tid * ND + j] * scale;
    } else if (blk < 392) {
        const int h = blk - 384;
        __shared__ float wog[32];   // WoWg[h*32 + jj]
        {
            const int jj = tid >> 3, sub = tid & 7;   // 8 lanes per jj
            const int j = h * 32 + jj;
            float acc = 0.f;
            const int m0 = sub * 36;                  // 288 = 8*36
            #pragma unroll 4
            for (int m = m0; m < m0 + 36; ++m)
                acc = fmaf(Wo[j * NDM + m], Wg[m], acc);
            acc += __shfl_down(acc, 4, 8);
            acc += __shfl_down(acc, 2, 8);
            acc += __shfl_down(acc, 1, 8);
            if (sub == 0) wog[jj] = acc;
        }
        __syncthreads();
        for (int e = tid; e < NDM; e += 256) {
            float acc = 0.f;
            #pragma unroll 8
            for (int jj = 0; jj < 32; ++jj)
                acc = fmaf(Wv[e * ND + h * 32 + jj], wog[jj], acc);
            VWo[h * NDM + e] = acc;
        }
        if (tid == 0) {
            float acc = 0.f;
            #pragma unroll 8
            for (int jj = 0; jj < 32; ++jj)
                acc = fmaf(bv[h * 32 + jj], wog[jj], acc);
            cst[8 + h] = acc;
        }
    } else {
        if (tid == 0) ws[OFF_CNT] = 0.0f;   // reset completion counter (int bits = 0)
        // cst[0..7]: 32 lanes per output
        const int i = tid >> 5, sub = tid & 31;
        float acc = 0.f;
        if (i < 6) {
            for (int m = sub; m < 256; m += 32)
                acc = fmaf(W_static[i * ND + m], Wg[NDM + m], acc);
        } else if (i == 6) {
            for (int m = sub; m < 256; m += 32)
                acc = fmaf(b_static[m], Wg[NDM + m], acc);
        } else {
            for (int m = sub; m < NDM; m += 32)
                acc = fmaf(bo[m], Wg[m], acc);
        }
        #pragma unroll
        for (int off = 16; off > 0; off >>= 1)
            acc += __shfl_down(acc, off, 32);
        if (sub == 0) cst[i] = (i == 6) ? acc + bg[0] : acc;
    }
}

__global__ __launch_bounds__(256) void main_kernel(
    const float* __restrict__ data, const int* __restrict__ lengths,
    const float* __restrict__ W_embed, const float* __restrict__ b_embed,
    const float* __restrict__ E_var,
    const float* __restrict__ Wq, const float* __restrict__ bq,
    const float* __restrict__ statics, float* __restrict__ out,
    float* __restrict__ ws)
{
    const int wg = blockIdx.x;        // b*23 + a
    const int a = wg % NA;
    const int tid = threadIdx.x;
    const int L = lengths[wg];        // wave-uniform

    __shared__ float xs[NT];
    __shared__ float agentwise[NDM];
    __shared__ float qs[ND];
    __shared__ float2 Wb[ND];
    // combo: per e<256, row of 20 floats (16 used): {qk[e][0..7], VWo[0..7][e], pad[4]}.
    // Row stride 20 (not 16): scalar stores at lane-stride 20 floats hit 8 distinct
    // 4-bank groups per 8 lanes -> 4-way conflict instead of 16-way at stride 16.
    // Reads in Phase E are wave-uniform broadcasts (conflict-free for any layout).
    // Dead after Phase E compute -> aliased as sc/mvb/partials (5120 floats total).
    __shared__ __align__(16) float combo[ND * 20];
    __shared__ float evvS[NH];
    __shared__ float red[4];
    __shared__ int lastFlag;

    const float* peT   = ws + OFF_PET;
    const float* PEcum = ws + OFF_PECUM;
    const float* WkT   = ws + OFF_WKT;
    const float* VWo   = ws + OFF_VWO;
    const float* cstp  = ws + OFF_CST;

    if (L > 0) {
        // ---- Phase A: load x row, W/b rows, agentwise via pe prefix table ----
        if (tid < NT) xs[tid] = data[wg * NT + tid];
        __syncthreads();
        {
            const int e = tid;   // 0..255
            const float We = W_embed[a * ND + e];
            const float be = b_embed[a * ND + e];
            Wb[e] = make_float2(We, be);
            // 4 accumulators: break the serial fp32 fma chain (ILP 4)
            float s0 = 0.f, s1 = 0.f, s2 = 0.f, s3 = 0.f;
            int t = 0;
            for (; t + 4 <= L; t += 4) {
                s0 += fmaxf(fmaf(xs[t],     We, be), 0.f);
                s1 += fmaxf(fmaf(xs[t + 1], We, be), 0.f);
                s2 += fmaxf(fmaf(xs[t + 2], We, be), 0.f);
                s3 += fmaxf(fmaf(xs[t + 3], We, be), 0.f);
            }
            for (; t < L; ++t)
                s0 += fmaxf(fmaf(xs[t], We, be), 0.f);
            agentwise[e] = (((s0 + s1) + (s2 + s3)) + PEcum[L * ND + e]) / (float)L;
        }
        if (tid < NAE) agentwise[ND + tid] = E_var[a * NAE + tid];
        __syncthreads();

        // ---- Phase C: q[j] = agentwise . Wq[:,j] + bq[j] ----
        // Each thread: 4 consecutive j via coalesced float4 loads of Wq,
        // over a 72-f chunk (fc wave-uniform); 4 independent acc chains of 72.
        {
            const int lane = tid & 63;
            const int fc = tid >> 6;            // wave-uniform
            const float4* Wq4 = (const float4*)Wq;
            float a0 = 0.f, a1 = 0.f, a2 = 0.f, a3 = 0.f;
            const int f0 = fc * 72;
            #pragma unroll 4
            for (int f = f0; f < f0 + 72; ++f) {
                const float ag = agentwise[f];          // LDS broadcast
                const float4 w = Wq4[f * 64 + lane];    // coalesced 16B/lane
                a0 = fmaf(ag, w.x, a0);
                a1 = fmaf(ag, w.y, a1);
                a2 = fmaf(ag, w.z, a2);
                a3 = fmaf(ag, w.w, a3);
            }
            ((float4*)combo)[fc * 64 + lane] = make_float4(a0, a1, a2, a3);
        }
        __syncthreads();
        qs[tid] = bq[tid] + combo[tid] + combo[256 + tid] + combo[512 + tid] + combo[768 + tid];
        __syncthreads();

        // ---- Phase D: qk[e][h] into combo (stride 20); copy VWo; evv ----
        {
            const int h = tid >> 5, eo = tid & 31;
            const float* wr = WkT + (h * 32) * 256;
            const float* qh = qs + h * 32;
            for (int eb = 0; eb < 8; ++eb) {
                const int e = eb * 32 + eo;
                float acc = 0.f, acc2 = 0.f;
                #pragma unroll
                for (int j = 0; j < 32; j += 2) {
                    acc  = fmaf(wr[ j      * 256 + e], qh[j],     acc);
                    acc2 = fmaf(wr[(j + 1) * 256 + e], qh[j + 1], acc2);
                }
                combo[e * 20 + h] = acc + acc2;
            }
        }
        for (int idx = tid; idx < NH * ND; idx += 256) {
            const int h = idx >> 8, e = idx & 255;
            combo[e * 20 + 8 + h] = VWo[h * NDM + e];
        }
        {
            const int h = tid >> 5, ee = tid & 31;
            float v = agentwise[ND + ee] * VWo[h * NDM + ND + ee];
            v += __shfl_down(v, 16, 32);
            v += __shfl_down(v, 8, 32);
            v += __shfl_down(v, 4, 32);
            v += __shfl_down(v, 2, 32);
            v += __shfl_down(v, 1, 32);
            if (ee == 0) evvS[h] = v;
        }
        __syncthreads();

        // ---- Phase E (L-adaptive): only t < Tpad computed.
        // L>64: P=2 chunks x 128 e each (as before). L<=64: P=4 chunks x 64 e
        // -> halves the dominant phase for ~half the blocks.
        {
            const int shift = (L > 64) ? 7 : 6;
            const int Tpad  = 1 << shift;       // threads-per-chunk == e's per thread
            const int P     = 256 >> shift;     // 2 or 4 chunks
            const int t     = tid & (Tpad - 1);
            const int c     = tid >> shift;     // wave-uniform chunk id
            const int ebase = c * Tpad;
            const float xt = xs[t];
            float accS[8], accM[8];
            #pragma unroll
            for (int h = 0; h < 8; ++h) { accS[h] = 0.f; accM[h] = 0.f; }
            const float4* comboV = (const float4*)combo;  // row = 5 float4s
            const float* peCol = peT + ebase * NT + t;
            #pragma unroll 2
            for (int ee = 0; ee < Tpad; ++ee) {
                const int e = ebase + ee;
                const float2 wb = Wb[e];
                const float m = fmaxf(fmaf(xt, wb.x, wb.y), 0.f) + peCol[ee * NT];
                const float4 c0 = comboV[e * 5 + 0];  // qk h0..3 (broadcast)
                const float4 c1 = comboV[e * 5 + 1];  // qk h4..7
                const float4 c2 = comboV[e * 5 + 2];  // VWo h0..3
                const float4 c3 = comboV[e * 5 + 3];  // VWo h4..7
                accS[0] = fmaf(m, c0.x, accS[0]);
                accS[1] = fmaf(m, c0.y, accS[1]);
                accS[2] = fmaf(m, c0.z, accS[2]);
                accS[3] = fmaf(m, c0.w, accS[3]);
                accS[4] = fmaf(m, c1.x, accS[4]);
                accS[5] = fmaf(m, c1.y, accS[5]);
                accS[6] = fmaf(m, c1.z, accS[6]);
                accS[7] = fmaf(m, c1.w, accS[7]);
                accM[0] = fmaf(m, c2.x, accM[0]);
                accM[1] = fmaf(m, c2.y, accM[1]);
                accM[2] = fmaf(m, c2.z, accM[2]);
                accM[3] = fmaf(m, c2.w, accM[3]);
                accM[4] = fmaf(m, c3.x, accM[4]);
                accM[5] = fmaf(m, c3.y, accM[5]);
                accM[6] = fmaf(m, c3.z, accM[6]);
                accM[7] = fmaf(m, c3.w, accM[7]);
            }
            __syncthreads();   // all combo reads done -> safe to reuse region
            float* sc  = combo;                 // final sc[h*128 + t]
            float* mvb = combo + 1024;          // final mvb[h*128 + t]
            float* sp  = combo + 2048;          // chunk partials (scores)
            float* mp  = sp + (P - 1) * 8 * Tpad;  // chunk partials (mv)
            if (c > 0) {
                float* spc = sp + (c - 1) * 8 * Tpad;
                float* mpc = mp + (c - 1) * 8 * Tpad;
                #pragma unroll
                for (int h = 0; h < 8; ++h) {
                    spc[h * Tpad + t] = accS[h];
                    mpc[h * Tpad + t] = accM[h];
                }
            }
            __syncthreads();
            if (c == 0) {
                #pragma unroll
                for (int h = 0; h < 8; ++h) {
                    float s = accS[h], m = accM[h];
                    for (int cc = 0; cc < P - 1; ++cc) {
                        s += sp[cc * 8 * Tpad + h * Tpad + t];
                        m += mp[cc * 8 * Tpad + h * Tpad + t];
                    }
                    sc[h * NT + t]  = s;
                    mvb[h * NT + t] = m;
                }
            }
        }
        __syncthreads();

        // ---- Phase F: per-head softmax over t<L, s_h = sum_t p*(mv+vb+evv) ----
        // (Entries t in [L, 128) of sc/mvb are stale-but-finite; masked by lane<L.)
        {
            const float* sc  = combo;
            const float* mvb = combo + 1024;
            const int wv = tid >> 6, lane = tid & 63;
            float wsum = 0.f;
            for (int hh = 0; hh < 2; ++hh) {
                const int h = wv * 2 + hh;
                float s1 = (lane < L) ? sc[h * NT + lane] : -3e38f;
                float s2 = (lane + 64 < L) ? sc[h * NT + 64 + lane] : -3e38f;
                float mx = fmaxf(s1, s2);
                #pragma unroll
                for (int off = 32; off > 0; off >>= 1)
                    mx = fmaxf(mx, __shfl_down(mx, off, 64));
                mx = __shfl(mx, 0, 64);
                const float vbv = evvS[h] + cstp[8 + h];
                float e1 = (lane < L) ? __expf(s1 - mx) : 0.f;
                float e2 = (lane + 64 < L) ? __expf(s2 - mx) : 0.f;
                float num = e1 * (mvb[h * NT + lane] + vbv);
                num = fmaf(e2, mvb[h * NT + 64 + lane] + vbv, num);
                float den = e1 + e2;
                #pragma unroll
                for (int off = 32; off > 0; off >>= 1) {
                    num += __shfl_down(num, off, 64);
                    den += __shfl_down(den, off, 64);
                }
                if (lane == 0) wsum += num / den;
            }
            if (lane == 0) red[wv] = wsum;
        }
        __syncthreads();
        if (tid == 0)
            ws[OFF_S + wg] = cstp[7] + red[0] + red[1] + red[2] + red[3];
    } else {
        if (tid == 0) ws[OFF_S + wg] = 0.f;
    }

    // ---- Completion counting + fused finalization (replaces final_kernel).
    // Release: threadfence before device-scope atomicAdd. The unique last block
    // acquires via fence and reads the s-array with device-coherent atomic reads
    // (plain loads could hit a stale non-coherent per-XCD L2).
    if (tid == 0) {
        __threadfence();
        const int prev = atomicAdd((int*)(ws + OFF_CNT), 1);
        lastFlag = (prev == NB * NA - 1) ? 1 : 0;
    }
    __syncthreads();
    if (lastFlag && tid < NB) {
        __threadfence();
        const int b = tid;
        float* s_arr = ws + OFF_S;
        float sum = 0.f;
        int n = 0;
        for (int aa = 0; aa < NA; ++aa) {
            if (lengths[b * NA + aa] > 0) {
                sum += atomicAdd(s_arr + b * NA + aa, 0.f);  // coherent read
                ++n;
            }
        }
        float o = sum / ((float)n + 1e-9f);
        #pragma unroll
        for (int i = 0; i < NS; ++i)
            o = fmaf(statics[b * NS + i], cstp[i], o);
        o += cstp[6];
        out[b] = o;
    }
}

extern "C" void kernel_launch(void* const* d_in, const int* in_sizes, int n_in,
                              void* d_out, int out_size, void* d_ws, size_t ws_size,
                              hipStream_t stream) {
    const float* data     = (const float*)d_in[0];
    // d_in[1] = time  (implied by mask; unused)
    const int*   mask     = (const int*)d_in[2];
    const float* statics  = (const float*)d_in[3];
    const float* W_embed  = (const float*)d_in[4];
    const float* b_embed  = (const float*)d_in[5];
    const float* E_var    = (const float*)d_in[6];
    const float* W_static = (const float*)d_in[7];
    const float* b_static = (const float*)d_in[8];
    const float* Wq       = (const float*)d_in[9];
    const float* bq       = (const float*)d_in[10];
    const float* Wk       = (const float*)d_in[11];
    // d_in[12] = bk (uniform over t -> cancels in softmax; unused)
    const float* Wv       = (const float*)d_in[13];
    const float* bv       = (const float*)d_in[14];
    const float* Wo       = (const float*)d_in[15];
    const float* bo       = (const float*)d_in[16];
    const float* Wg       = (const float*)d_in[17];
    const float* bg       = (const float*)d_in[18];
    float* out = (float*)d_out;
    float* ws  = (float*)d_ws;

    setup_kernel<<<dim3(393), dim3(256), 0, stream>>>(Wk, Wv, Wo, Wg, bv, bo,
                                                      W_static, b_static, bg, ws);
    main_kernel<<<dim3(NB * NA), dim3(256), 0, stream>>>(data, mask, W_embed, b_embed,
                                                         E_var, Wq, bq, statics, out, ws);
}

// Round 2
// 192.432 us; speedup vs baseline: 1.1153x; 1.1153x over previous
//
#include <hip/hip_runtime.h>
#include <math.h>

// Problem dims
#define NB 64
#define NA 23
#define NT 128
#define ND 256
#define NAE 32
#define NS 6
#define NH 8
#define NDM 288

// Workspace layout (float offsets)
#define OFF_PET    0                 // peT[e][t] : 256*128
#define OFF_PECUM  32768             // PEcum[L][e] : 129*256 (rows 1..128 used)
#define OFF_WKS    65792             // WkS[e][j] = Wk[e][j]/sqrt(32), e<256 : 256*256 row-major
#define OFF_VWO    131328            // VWo[h][e] : 8*288
#define OFF_CST    133632            // [0..5]=sWf, [6]=b_static.Wg1+bg, [7]=bo.Wg0, [8..15]=vb[h]
#define OFF_S      133648            // s[b][a] : 1472
// total floats = 135120 (540,480 bytes of ws)

// Parallel setup: 201 blocks.
//  blocks [0,128)   : pe table + prefix scan, 2 e-columns per block
//  blocks [128,192) : WkS scaled copy (row-major, fully coalesced float4)
//  blocks [192,200) : per-head VWo (+ redundant WoWg slice) + cst[8+h]
//  block  200       : cst[0..7]
__global__ __launch_bounds__(256) void setup_kernel(
    const float* __restrict__ Wk, const float* __restrict__ Wv,
    const float* __restrict__ Wo, const float* __restrict__ Wg,
    const float* __restrict__ bv, const float* __restrict__ bo,
    const float* __restrict__ W_static, const float* __restrict__ b_static,
    const float* __restrict__ bg, float* __restrict__ ws)
{
    const int blk = blockIdx.x;
    const int tid = threadIdx.x;
    float* peT   = ws + OFF_PET;
    float* PEcum = ws + OFF_PECUM;
    float* VWo   = ws + OFF_VWO;
    float* cst   = ws + OFF_CST;

    if (blk < 128) {
        // pe: e = blk*2 + (tid>>7), t = tid&127. One transcendental per thread.
        const int g = tid >> 7, t = tid & 127;
        const int e = blk * 2 + g;
        const int i = e >> 1;
        const float kdiv = 0.07195578415606394f; // ln(10000)/128
        const float dv = expf(-(float)i * kdiv);
        const float ang = (float)t * dv;
        const float v = (e & 1) ? cosf(ang) : sinf(ang);
        peT[e * NT + t] = v;
        __shared__ float buf[256];
        buf[tid] = v;
        // inclusive Hillis-Steele scan over t within each 128-group
        #pragma unroll
        for (int s = 1; s < 128; s <<= 1) {
            __syncthreads();
            float add = (t >= s) ? buf[tid - s] : 0.f;
            __syncthreads();
            buf[tid] += add;
        }
        __syncthreads();
        PEcum[(t + 1) * ND + e] = buf[tid];
    } else if (blk < 192) {
        // WkS = Wk[0:256][:] * 1/sqrt(32), row-major (E_var rows cancel in softmax).
        // 16384 float4s over 64 blocks x 256 threads: one float4 each, coalesced.
        const float scale = 0.17677669529663687f;
        const int i = (blk - 128) * 256 + tid;
        const float4 w = ((const float4*)Wk)[i];
        ((float4*)(ws + OFF_WKS))[i] = make_float4(w.x * scale, w.y * scale,
                                                   w.z * scale, w.w * scale);
    } else if (blk < 200) {
        const int h = blk - 192;
        __shared__ float wog[32];   // WoWg[h*32 + jj]
        {
            const int jj = tid >> 3, sub = tid & 7;   // 8 lanes per jj
            const int j = h * 32 + jj;
            float acc = 0.f;
            const int m0 = sub * 36;                  // 288 = 8*36
            #pragma unroll 4
            for (int m = m0; m < m0 + 36; ++m)
                acc = fmaf(Wo[j * NDM + m], Wg[m], acc);
            acc += __shfl_down(acc, 4, 8);
            acc += __shfl_down(acc, 2, 8);
            acc += __shfl_down(acc, 1, 8);
            if (sub == 0) wog[jj] = acc;
        }
        __syncthreads();
        for (int e = tid; e < NDM; e += 256) {
            float acc = 0.f;
            #pragma unroll 8
            for (int jj = 0; jj < 32; ++jj)
                acc = fmaf(Wv[e * ND + h * 32 + jj], wog[jj], acc);
            VWo[h * NDM + e] = acc;
        }
        if (tid == 0) {
            float acc = 0.f;
            #pragma unroll 8
            for (int jj = 0; jj < 32; ++jj)
                acc = fmaf(bv[h * 32 + jj], wog[jj], acc);
            cst[8 + h] = acc;
        }
    } else {
        // cst[0..7]: 32 lanes per output
        const int i = tid >> 5, sub = tid & 31;
        float acc = 0.f;
        if (i < 6) {
            for (int m = sub; m < 256; m += 32)
                acc = fmaf(W_static[i * ND + m], Wg[NDM + m], acc);
        } else if (i == 6) {
            for (int m = sub; m < 256; m += 32)
                acc = fmaf(b_static[m], Wg[NDM + m], acc);
        } else {
            for (int m = sub; m < NDM; m += 32)
                acc = fmaf(bo[m], Wg[m], acc);
        }
        #pragma unroll
        for (int off = 16; off > 0; off >>= 1)
            acc += __shfl_down(acc, off, 32);
        if (sub == 0) cst[i] = (i == 6) ? acc + bg[0] : acc;
    }
}

// Phase E body: logical float4 slot j of row e lives at physical slot j ^ (e&3).
// RR is a compile-time constant = e&3 (ebase is a multiple of 4).
#define EBODY(EE, RR) do {                                                   \
    const int e_ = ebase + (EE);                                             \
    const float2 wb = Wb[e_];                                                \
    const float m = fmaxf(fmaf(xt, wb.x, wb.y), 0.f) + pcur[RR];             \
    const float4 c0 = comboV[e_ * 4 + (0 ^ (RR))];                           \
    const float4 c1 = comboV[e_ * 4 + (1 ^ (RR))];                           \
    const float4 c2 = comboV[e_ * 4 + (2 ^ (RR))];                           \
    const float4 c3 = comboV[e_ * 4 + (3 ^ (RR))];                           \
    accS[0] = fmaf(m, c0.x, accS[0]); accS[1] = fmaf(m, c0.y, accS[1]);      \
    accS[2] = fmaf(m, c0.z, accS[2]); accS[3] = fmaf(m, c0.w, accS[3]);      \
    accS[4] = fmaf(m, c1.x, accS[4]); accS[5] = fmaf(m, c1.y, accS[5]);      \
    accS[6] = fmaf(m, c1.z, accS[6]); accS[7] = fmaf(m, c1.w, accS[7]);      \
    accM[0] = fmaf(m, c2.x, accM[0]); accM[1] = fmaf(m, c2.y, accM[1]);      \
    accM[2] = fmaf(m, c2.z, accM[2]); accM[3] = fmaf(m, c2.w, accM[3]);      \
    accM[4] = fmaf(m, c3.x, accM[4]); accM[5] = fmaf(m, c3.y, accM[5]);      \
    accM[6] = fmaf(m, c3.z, accM[6]); accM[7] = fmaf(m, c3.w, accM[7]);      \
} while (0)

// Software-pipelined loop over TPC e-values (TPC a compile-time constant,
// multiple of 4). pe loads run one 4-group ahead; the final over-read lands
// in PEcum (valid ws memory), values unused.
#define E_LOOP(TPC)                                                          \
    pcur[0] = peCol[0 * NT]; pcur[1] = peCol[1 * NT];                        \
    pcur[2] = peCol[2 * NT]; pcur[3] = peCol[3 * NT];                        \
    _Pragma("unroll 2")                                                      \
    for (int ee = 0; ee < (TPC); ee += 4) {                                  \
        const float pn0 = peCol[(ee + 4) * NT];                              \
        const float pn1 = peCol[(ee + 5) * NT];                              \
        const float pn2 = peCol[(ee + 6) * NT];                              \
        const float pn3 = peCol[(ee + 7) * NT];                              \
        EBODY(ee + 0, 0); EBODY(ee + 1, 1);                                  \
        EBODY(ee + 2, 2); EBODY(ee + 3, 3);                                  \
        pcur[0] = pn0; pcur[1] = pn1; pcur[2] = pn2; pcur[3] = pn3;          \
    }

__global__ __launch_bounds__(256) void main_kernel(
    const float* __restrict__ data, const int* __restrict__ lengths,
    const float* __restrict__ W_embed, const float* __restrict__ b_embed,
    const float* __restrict__ E_var,
    const float* __restrict__ Wq, const float* __restrict__ bq,
    float* __restrict__ ws)
{
    const int wg = blockIdx.x;        // b*23 + a
    const int a = wg % NA;
    const int tid = threadIdx.x;
    const int L = lengths[wg];        // wave-uniform

    if (L == 0) {
        if (tid == 0) ws[OFF_S + wg] = 0.f;
        return;
    }

    __shared__ float xs[NT];
    __shared__ float agentwise[NDM];
    __shared__ __align__(16) float qs[ND];
    __shared__ float2 Wb[ND];
    // combo: per e<256, 4 float4s {qk h0-3, qk h4-7, VWo h0-3, VWo h4-7},
    // XOR-swizzled at float4 granularity (slot j^(e&3)) -> store conflicts
    // drop 16-way -> 2-way with NO padding (LDS unchanged vs round 0).
    // Dead after Phase E compute -> aliased as sc/mvb/partials.
    __shared__ __align__(16) float combo[ND * 16];
    __shared__ float evvS[NH];
    __shared__ float red[4];

    const float* peT   = ws + OFF_PET;
    const float* PEcum = ws + OFF_PECUM;
    const float* WkS   = ws + OFF_WKS;
    const float* VWo   = ws + OFF_VWO;
    const float* cstp  = ws + OFF_CST;

    // ---- Phase A: load x row, W/b rows, agentwise via pe prefix table ----
    if (tid < NT) xs[tid] = data[wg * NT + tid];
    __syncthreads();
    {
        const int e = tid;   // 0..255
        const float We = W_embed[a * ND + e];
        const float be = b_embed[a * ND + e];
        Wb[e] = make_float2(We, be);
        float s0 = 0.f, s1 = 0.f, s2 = 0.f, s3 = 0.f;
        int t = 0;
        for (; t + 4 <= L; t += 4) {
            s0 += fmaxf(fmaf(xs[t],     We, be), 0.f);
            s1 += fmaxf(fmaf(xs[t + 1], We, be), 0.f);
            s2 += fmaxf(fmaf(xs[t + 2], We, be), 0.f);
            s3 += fmaxf(fmaf(xs[t + 3], We, be), 0.f);
        }
        for (; t < L; ++t)
            s0 += fmaxf(fmaf(xs[t], We, be), 0.f);
        agentwise[e] = (((s0 + s1) + (s2 + s3)) + PEcum[L * ND + e]) / (float)L;
    }
    if (tid < NAE) agentwise[ND + tid] = E_var[a * NAE + tid];
    __syncthreads();

    // ---- Phase C: q[j] = agentwise . Wq[:,j] + bq[j] ----
    // 4 consecutive j per thread via coalesced float4 loads of Wq over a
    // wave-uniform 72-f chunk; partials in combo scratch, reduced into qs.
    {
        const int lane = tid & 63;
        const int fc = tid >> 6;            // wave-uniform
        const float4* Wq4 = (const float4*)Wq;
        float a0 = 0.f, a1 = 0.f, a2 = 0.f, a3 = 0.f;
        const int f0 = fc * 72;
        #pragma unroll 4
        for (int f = f0; f < f0 + 72; ++f) {
            const float ag = agentwise[f];          // LDS broadcast
            const float4 w = Wq4[f * 64 + lane];    // coalesced 16B/lane
            a0 = fmaf(ag, w.x, a0);
            a1 = fmaf(ag, w.y, a1);
            a2 = fmaf(ag, w.z, a2);
            a3 = fmaf(ag, w.w, a3);
        }
        ((float4*)combo)[fc * 64 + lane] = make_float4(a0, a1, a2, a3);
    }
    __syncthreads();
    qs[tid] = bq[tid] + combo[tid] + combo[256 + tid] + combo[512 + tid] + combo[768 + tid];
    __syncthreads();

    // ---- Phase D: thread e owns combo row e: 8 qk dots + 8 VWo values.
    // WkS row-major: 64 float4 loads w/ immediate offsets (no addr math),
    // qs via float4 LDS broadcast. 4 ds_write_b128, XOR-swizzled (2-way). ----
    {
        const int e = tid;
        const float4* wrow = (const float4*)(WkS + e * 256);
        const float4* qs4  = (const float4*)qs;
        float qk[8];
        #pragma unroll
        for (int h = 0; h < 8; ++h) {
            float a0 = 0.f, a1 = 0.f, a2 = 0.f, a3 = 0.f;
            #pragma unroll
            for (int jq = 0; jq < 8; ++jq) {
                const float4 w = wrow[h * 8 + jq];
                const float4 q = qs4[h * 8 + jq];   // broadcast
                a0 = fmaf(w.x, q.x, a0);
                a1 = fmaf(w.y, q.y, a1);
                a2 = fmaf(w.z, q.z, a2);
                a3 = fmaf(w.w, q.w, a3);
            }
            qk[h] = (a0 + a1) + (a2 + a3);
        }
        float vwo[8];
        #pragma unroll
        for (int h = 0; h < 8; ++h) vwo[h] = VWo[h * NDM + e];  // coalesced
        const int r = e & 3;
        float4* row = (float4*)combo + e * 4;
        row[0 ^ r] = make_float4(qk[0], qk[1], qk[2], qk[3]);
        row[1 ^ r] = make_float4(qk[4], qk[5], qk[6], qk[7]);
        row[2 ^ r] = make_float4(vwo[0], vwo[1], vwo[2], vwo[3]);
        row[3 ^ r] = make_float4(vwo[4], vwo[5], vwo[6], vwo[7]);
    }
    {
        const int h = tid >> 5, ee = tid & 31;
        float v = agentwise[ND + ee] * VWo[h * NDM + ND + ee];
        v += __shfl_down(v, 16, 32);
        v += __shfl_down(v, 8, 32);
        v += __shfl_down(v, 4, 32);
        v += __shfl_down(v, 2, 32);
        v += __shfl_down(v, 1, 32);
        if (ee == 0) evvS[h] = v;
    }
    __syncthreads();

    // ---- Phase E + F: two compile-time paths branched on wave-uniform L ----
    const float4* comboV = (const float4*)combo;
    if (L > 64) {
        // 2 chunks x 128 e, t in [0,128)
        const int t = tid & 127, half = tid >> 7;
        const int ebase = half * 128;
        const float xt = xs[t];
        const float* peCol = peT + ebase * NT + t;
        float pcur[4];
        float accS[8], accM[8];
        #pragma unroll
        for (int h = 0; h < 8; ++h) { accS[h] = 0.f; accM[h] = 0.f; }
        E_LOOP(128);
        __syncthreads();   // all combo reads done -> reuse region
        float* sc   = combo;
        float* mvb  = combo + 1024;
        float* scP1 = combo + 2048;
        float* mvP1 = combo + 3072;
        if (half == 1) {
            #pragma unroll
            for (int h = 0; h < 8; ++h) {
                scP1[h * NT + t] = accS[h];
                mvP1[h * NT + t] = accM[h];
            }
        }
        __syncthreads();
        if (half == 0) {
            #pragma unroll
            for (int h = 0; h < 8; ++h) {
                sc[h * NT + t]  = accS[h] + scP1[h * NT + t];
                mvb[h * NT + t] = accM[h] + mvP1[h * NT + t];
            }
        }
        __syncthreads();
        // Phase F (128-wide layout)
        {
            const int wv = tid >> 6, lane = tid & 63;
            float wsum = 0.f;
            for (int hh = 0; hh < 2; ++hh) {
                const int h = wv * 2 + hh;
                float s1 = (lane < L) ? sc[h * NT + lane] : -3e38f;
                float s2 = (lane + 64 < L) ? sc[h * NT + 64 + lane] : -3e38f;
                float mx = fmaxf(s1, s2);
                #pragma unroll
                for (int off = 32; off > 0; off >>= 1)
                    mx = fmaxf(mx, __shfl_down(mx, off, 64));
                mx = __shfl(mx, 0, 64);
                const float vbv = evvS[h] + cstp[8 + h];
                float e1 = (lane < L) ? __expf(s1 - mx) : 0.f;
                float e2 = (lane + 64 < L) ? __expf(s2 - mx) : 0.f;
                float num = e1 * (mvb[h * NT + lane] + vbv);
                num = fmaf(e2, mvb[h * NT + 64 + lane] + vbv, num);
                float den = e1 + e2;
                #pragma unroll
                for (int off = 32; off > 0; off >>= 1) {
                    num += __shfl_down(num, off, 64);
                    den += __shfl_down(den, off, 64);
                }
                if (lane == 0) wsum += num / den;
            }
            if (lane == 0) red[wv] = wsum;
        }
    } else {
        // 4 chunks x 64 e, t in [0,64): half the inner loop for L<=64 blocks
        const int t = tid & 63, c = tid >> 6;
        const int ebase = c * 64;
        const float xt = xs[t];
        const float* peCol = peT + ebase * NT + t;
        float pcur[4];
        float accS[8], accM[8];
        #pragma unroll
        for (int h = 0; h < 8; ++h) { accS[h] = 0.f; accM[h] = 0.f; }
        E_LOOP(64);
        __syncthreads();
        // compact 64-wide layout: sc [0,512), mvb [512,1024), partials [1024,4096)
        float* sc  = combo;
        float* mvb = combo + 512;
        float* sp  = combo + 1024;   // per chunk c>0: [S 512][M 512]
        if (c > 0) {
            float* bse = sp + (c - 1) * 1024;
            #pragma unroll
            for (int h = 0; h < 8; ++h) {
                bse[h * 64 + t]       = accS[h];
                bse[512 + h * 64 + t] = accM[h];
            }
        }
        __syncthreads();
        if (c == 0) {
            #pragma unroll
            for (int h = 0; h < 8; ++h) {
                float s = accS[h] + sp[h * 64 + t] + sp[1024 + h * 64 + t]
                                  + sp[2048 + h * 64 + t];
                float m = accM[h] + sp[512 + h * 64 + t] + sp[1536 + h * 64 + t]
                                  + sp[2560 + h * 64 + t];
                sc[h * 64 + t]  = s;
                mvb[h * 64 + t] = m;
            }
        }
        __syncthreads();
        // Phase F (64-wide layout, single segment)
        {
            const int wv = tid >> 6, lane = tid & 63;
            float wsum = 0.f;
            for (int hh = 0; hh < 2; ++hh) {
                const int h = wv * 2 + hh;
                float s1 = (lane < L) ? sc[h * 64 + lane] : -3e38f;
                float mx = s1;
                #pragma unroll
                for (int off = 32; off > 0; off >>= 1)
                    mx = fmaxf(mx, __shfl_down(mx, off, 64));
                mx = __shfl(mx, 0, 64);
                const float vbv = evvS[h] + cstp[8 + h];
                float e1 = (lane < L) ? __expf(s1 - mx) : 0.f;
                float num = e1 * (mvb[h * 64 + lane] + vbv);
                float den = e1;
                #pragma unroll
                for (int off = 32; off > 0; off >>= 1) {
                    num += __shfl_down(num, off, 64);
                    den += __shfl_down(den, off, 64);
                }
                if (lane == 0) wsum += num / den;
            }
            if (lane == 0) red[wv] = wsum;
        }
    }
    __syncthreads();
    if (tid == 0)
        ws[OFF_S + wg] = cstp[7] + red[0] + red[1] + red[2] + red[3];
}

__global__ __launch_bounds__(64) void final_kernel(
    const float* __restrict__ statics, const int* __restrict__ lengths,
    const float* __restrict__ ws, float* __restrict__ out)
{
    const int b = threadIdx.x;   // 64 threads, one per batch
    const float* s_arr = ws + OFF_S;
    const float* cst = ws + OFF_CST;
    float sum = 0.f;
    int n = 0;
    for (int a = 0; a < NA; ++a) {
        if (lengths[b * NA + a] > 0) { sum += s_arr[b * NA + a]; ++n; }
    }
    float o = sum / ((float)n + 1e-9f);
    #pragma unroll
    for (int i = 0; i < NS; ++i)
        o = fmaf(statics[b * NS + i], cst[i], o);
    o += cst[6];
    out[b] = o;
}

extern "C" void kernel_launch(void* const* d_in, const int* in_sizes, int n_in,
                              void* d_out, int out_size, void* d_ws, size_t ws_size,
                              hipStream_t stream) {
    const float* data     = (const float*)d_in[0];
    // d_in[1] = time  (implied by mask; unused)
    const int*   mask     = (const int*)d_in[2];
    const float* statics  = (const float*)d_in[3];
    const float* W_embed  = (const float*)d_in[4];
    const float* b_embed  = (const float*)d_in[5];
    const float* E_var    = (const float*)d_in[6];
    const float* W_static = (const float*)d_in[7];
    const float* b_static = (const float*)d_in[8];
    const float* Wq       = (const float*)d_in[9];
    const float* bq       = (const float*)d_in[10];
    const float* Wk       = (const float*)d_in[11];
    // d_in[12] = bk (uniform over t -> cancels in softmax; unused)
    const float* Wv       = (const float*)d_in[13];
    const float* bv       = (const float*)d_in[14];
    const float* Wo       = (const float*)d_in[15];
    const float* bo       = (const float*)d_in[16];
    const float* Wg       = (const float*)d_in[17];
    const float* bg       = (const float*)d_in[18];
    float* out = (float*)d_out;
    float* ws  = (float*)d_ws;

    setup_kernel<<<dim3(201), dim3(256), 0, stream>>>(Wk, Wv, Wo, Wg, bv, bo,
                                                      W_static, b_static, bg, ws);
    main_kernel<<<dim3(NB * NA), dim3(256), 0, stream>>>(data, mask, W_embed, b_embed,
                                                         E_var, Wq, bq, ws);
    final_kernel<<<dim3(1), dim3(64), 0, stream>>>(statics, mask, ws, out);
}

// Round 3
// 174.417 us; speedup vs baseline: 1.2305x; 1.1033x over previous
//
#include <hip/hip_runtime.h>
#include <math.h>

// Problem dims
#define NB 64
#define NA 23
#define NT 128
#define ND 256
#define NAE 32
#define NS 6
#define NH 8
#define NDM 288

// Workspace layout (float offsets)
#define OFF_PET    0                 // peT[e][t] : 256*128
#define OFF_PECUM  32768             // PEcum[L][e] : 129*256 (rows 1..128 used)
#define OFF_WKT    65792             // WkT[j][e<256] = Wk[e][j]/sqrt(32) : 256*256
#define OFF_VWO    131328            // VWo[h][e] : 8*288
#define OFF_CST    133632            // [0..5]=sWf, [6]=b_static.Wg1+bg, [7]=bo.Wg0, [8..15]=vb[h]
#define OFF_S      133648            // s[b][a] : 1472
// total floats = 135120 (540,480 bytes of ws)

// Parallel setup: 393 blocks (round-0 structure).
//  blocks [0,128)   : pe table + prefix scan, 2 e-columns per block
//  blocks [128,384) : WkT transpose, one j-row per block
//  blocks [384,392) : per-head VWo (+ redundant WoWg slice) + cst[8+h]
//  block  392       : cst[0..7]
__global__ __launch_bounds__(256) void setup_kernel(
    const float* __restrict__ Wk, const float* __restrict__ Wv,
    const float* __restrict__ Wo, const float* __restrict__ Wg,
    const float* __restrict__ bv, const float* __restrict__ bo,
    const float* __restrict__ W_static, const float* __restrict__ b_static,
    const float* __restrict__ bg, float* __restrict__ ws)
{
    const int blk = blockIdx.x;
    const int tid = threadIdx.x;
    float* peT   = ws + OFF_PET;
    float* PEcum = ws + OFF_PECUM;
    float* WkT   = ws + OFF_WKT;
    float* VWo   = ws + OFF_VWO;
    float* cst   = ws + OFF_CST;

    if (blk < 128) {
        // pe: e = blk*2 + (tid>>7), t = tid&127. One transcendental per thread.
        const int g = tid >> 7, t = tid & 127;
        const int e = blk * 2 + g;
        const int i = e >> 1;
        const float kdiv = 0.07195578415606394f; // ln(10000)/128
        const float dv = expf(-(float)i * kdiv);
        const float ang = (float)t * dv;
        const float v = (e & 1) ? cosf(ang) : sinf(ang);
        peT[e * NT + t] = v;
        __shared__ float buf[256];
        buf[tid] = v;
        // inclusive Hillis-Steele scan over t within each 128-group
        #pragma unroll
        for (int s = 1; s < 128; s <<= 1) {
            __syncthreads();
            float add = (t >= s) ? buf[tid - s] : 0.f;
            __syncthreads();
            buf[tid] += add;
        }
        __syncthreads();
        PEcum[(t + 1) * ND + e] = buf[tid];
    } else if (blk < 384) {
        // WkT[j][e] = Wk[e][j] * 1/sqrt(32), e<256 only (E_var cols cancel in softmax)
        const int j = blk - 128;
        const float scale = 0.17677669529663687f;
        WkT[j * 256 + tid] = Wk[tid * ND + j] * scale;
    } else if (blk < 392) {
        const int h = blk - 384;
        __shared__ float wog[32];   // WoWg[h*32 + jj]
        {
            const int jj = tid >> 3, sub = tid & 7;   // 8 lanes per jj
            const int j = h * 32 + jj;
            float acc = 0.f;
            const int m0 = sub * 36;                  // 288 = 8*36
            #pragma unroll 4
            for (int m = m0; m < m0 + 36; ++m)
                acc = fmaf(Wo[j * NDM + m], Wg[m], acc);
            acc += __shfl_down(acc, 4, 8);
            acc += __shfl_down(acc, 2, 8);
            acc += __shfl_down(acc, 1, 8);
            if (sub == 0) wog[jj] = acc;
        }
        __syncthreads();
        for (int e = tid; e < NDM; e += 256) {
            float acc = 0.f;
            #pragma unroll 8
            for (int jj = 0; jj < 32; ++jj)
                acc = fmaf(Wv[e * ND + h * 32 + jj], wog[jj], acc);
            VWo[h * NDM + e] = acc;
        }
        if (tid == 0) {
            float acc = 0.f;
            #pragma unroll 8
            for (int jj = 0; jj < 32; ++jj)
                acc = fmaf(bv[h * 32 + jj], wog[jj], acc);
            cst[8 + h] = acc;
        }
    } else {
        // cst[0..7]: 32 lanes per output
        const int i = tid >> 5, sub = tid & 31;
        float acc = 0.f;
        if (i < 6) {
            for (int m = sub; m < 256; m += 32)
                acc = fmaf(W_static[i * ND + m], Wg[NDM + m], acc);
        } else if (i == 6) {
            for (int m = sub; m < 256; m += 32)
                acc = fmaf(b_static[m], Wg[NDM + m], acc);
        } else {
            for (int m = sub; m < NDM; m += 32)
                acc = fmaf(bo[m], Wg[m], acc);
        }
        #pragma unroll
        for (int off = 16; off > 0; off >>= 1)
            acc += __shfl_down(acc, off, 32);
        if (sub == 0) cst[i] = (i == 6) ? acc + bg[0] : acc;
    }
}

__global__ __launch_bounds__(256) void main_kernel(
    const float* __restrict__ data, const int* __restrict__ lengths,
    const float* __restrict__ W_embed, const float* __restrict__ b_embed,
    const float* __restrict__ E_var,
    const float* __restrict__ Wq, const float* __restrict__ bq,
    float* __restrict__ ws)
{
    const int wg = blockIdx.x;        // b*23 + a
    const int a = wg % NA;
    const int tid = threadIdx.x;
    const int L = lengths[wg];        // wave-uniform

    if (L == 0) {
        if (tid == 0) ws[OFF_S + wg] = 0.f;
        return;
    }

    __shared__ float xs[NT];
    __shared__ float agentwise[NDM];
    __shared__ float qs[ND];
    __shared__ float2 Wb[ND];
    // combo: per e<256, row of 20 floats (16 used): {qk[e][0..7], VWo[0..7][e], pad4}.
    // Stride 20: Phase-D scalar stores (lane-stride 20 floats) hit 8 distinct
    // 4-bank groups -> 4-way conflict instead of 16-way at stride 16 (round-1
    // measured: 2.79M -> 0.56M). Phase-E reads are wave-uniform float4
    // broadcasts (conflict-free for any layout).
    // Dead after Phase E compute -> aliased as sc/mvb/partials (4096 floats used).
    __shared__ __align__(16) float combo[ND * 20];
    __shared__ float evvS[NH];
    __shared__ float red[4];

    const float* peT   = ws + OFF_PET;
    const float* PEcum = ws + OFF_PECUM;
    const float* WkT   = ws + OFF_WKT;
    const float* VWo   = ws + OFF_VWO;
    const float* cstp  = ws + OFF_CST;

    // ---- Phase A: load x row, W/b rows, agentwise via pe prefix table ----
    if (tid < NT) xs[tid] = data[wg * NT + tid];
    __syncthreads();
    {
        const int e = tid;   // 0..255
        const float We = W_embed[a * ND + e];
        const float be = b_embed[a * ND + e];
        Wb[e] = make_float2(We, be);
        float s0 = 0.f, s1 = 0.f, s2 = 0.f, s3 = 0.f;
        int t = 0;
        for (; t + 4 <= L; t += 4) {
            s0 += fmaxf(fmaf(xs[t],     We, be), 0.f);
            s1 += fmaxf(fmaf(xs[t + 1], We, be), 0.f);
            s2 += fmaxf(fmaf(xs[t + 2], We, be), 0.f);
            s3 += fmaxf(fmaf(xs[t + 3], We, be), 0.f);
        }
        for (; t < L; ++t)
            s0 += fmaxf(fmaf(xs[t], We, be), 0.f);
        agentwise[e] = (((s0 + s1) + (s2 + s3)) + PEcum[L * ND + e]) / (float)L;
    }
    if (tid < NAE) agentwise[ND + tid] = E_var[a * NAE + tid];
    __syncthreads();

    // ---- Phase C: q[j] = agentwise . Wq[:,j] + bq[j] (round-0 coalesced form) ----
    {
        const int j = tid;
        float acc = bq[j];
        #pragma unroll 4
        for (int f = 0; f < NDM; ++f)
            acc = fmaf(agentwise[f], Wq[f * ND + j], acc);
        qs[j] = acc;
    }
    __syncthreads();

    // ---- Phase D: qk[e][h] into combo (stride 20); copy VWo; evv ----
    {
        const int h = tid >> 5, eo = tid & 31;
        const float* wr = WkT + (h * 32) * 256;
        const float* qh = qs + h * 32;
        for (int eb = 0; eb < 8; ++eb) {
            const int e = eb * 32 + eo;
            float acc = 0.f, acc2 = 0.f;
            #pragma unroll
            for (int j = 0; j < 32; j += 2) {
                acc  = fmaf(wr[ j      * 256 + e], qh[j],     acc);
                acc2 = fmaf(wr[(j + 1) * 256 + e], qh[j + 1], acc2);
            }
            combo[e * 20 + h] = acc + acc2;
        }
    }
    for (int idx = tid; idx < NH * ND; idx += 256) {
        const int h = idx >> 8, e = idx & 255;
        combo[e * 20 + 8 + h] = VWo[h * NDM + e];
    }
    {
        const int h = tid >> 5, ee = tid & 31;
        float v = agentwise[ND + ee] * VWo[h * NDM + ND + ee];
        v += __shfl_down(v, 16, 32);
        v += __shfl_down(v, 8, 32);
        v += __shfl_down(v, 4, 32);
        v += __shfl_down(v, 2, 32);
        v += __shfl_down(v, 1, 32);
        if (ee == 0) evvS[h] = v;
    }
    __syncthreads();

    // ---- Phase E: h-split + t-pair.
    // Thread = (t in [0,64), hh = head-half, c = e-chunk of 128).
    // Each thread handles TWO t values (t, t+64) but reads only 2 broadcast
    // float4s per e (its h-half) -> halves wave-wide ds_read_b128 count vs
    // round 0 at EQUAL accumulator count (16) -> VGPR stays in the 8-wave bucket.
    {
        const int t  = tid & 63;
        const int hh = (tid >> 6) & 1;   // wave-uniform
        const int c  = tid >> 7;         // wave-uniform
        const int ebase = c * 128;
        const float xt1 = xs[t];
        const float xt2 = xs[t + 64];
        const float* peCol = peT + ebase * NT + t;
        const float4* comboV = (const float4*)combo;  // row = 5 float4s
        float aS1[4], aS2[4], aM1[4], aM2[4];
        #pragma unroll
        for (int k = 0; k < 4; ++k) { aS1[k] = 0.f; aS2[k] = 0.f; aM1[k] = 0.f; aM2[k] = 0.f; }

        if (L > 64) {
            #pragma unroll 2
            for (int ee = 0; ee < 128; ++ee) {
                const int e = ebase + ee;
                const float2 wb = Wb[e];
                const float pe1 = peCol[ee * NT];
                const float pe2 = peCol[ee * NT + 64];
                const float lin1 = fmaf(xt1, wb.x, wb.y);
                const float lin2 = fmaf(xt2, wb.x, wb.y);
                const float m1 = fmaxf(lin1, 0.f) + pe1;
                const float m2 = fmaxf(lin2, 0.f) + pe2;
                const float4 cq = comboV[e * 5 + hh];      // qk quad (broadcast)
                const float4 cm = comboV[e * 5 + 2 + hh];  // VWo quad (broadcast)
                aS1[0] = fmaf(m1, cq.x, aS1[0]); aS1[1] = fmaf(m1, cq.y, aS1[1]);
                aS1[2] = fmaf(m1, cq.z, aS1[2]); aS1[3] = fmaf(m1, cq.w, aS1[3]);
                aS2[0] = fmaf(m2, cq.x, aS2[0]); aS2[1] = fmaf(m2, cq.y, aS2[1]);
                aS2[2] = fmaf(m2, cq.z, aS2[2]); aS2[3] = fmaf(m2, cq.w, aS2[3]);
                aM1[0] = fmaf(m1, cm.x, aM1[0]); aM1[1] = fmaf(m1, cm.y, aM1[1]);
                aM1[2] = fmaf(m1, cm.z, aM1[2]); aM1[3] = fmaf(m1, cm.w, aM1[3]);
                aM2[0] = fmaf(m2, cm.x, aM2[0]); aM2[1] = fmaf(m2, cm.y, aM2[1]);
                aM2[2] = fmaf(m2, cm.z, aM2[2]); aM2[3] = fmaf(m2, cm.w, aM2[3]);
            }
        } else {
            // t+64 >= 64 >= L is always masked in Phase F -> skip second-t work.
            #pragma unroll 2
            for (int ee = 0; ee < 128; ++ee) {
                const int e = ebase + ee;
                const float2 wb = Wb[e];
                const float pe1 = peCol[ee * NT];
                const float m1 = fmaxf(fmaf(xt1, wb.x, wb.y), 0.f) + pe1;
                const float4 cq = comboV[e * 5 + hh];
                const float4 cm = comboV[e * 5 + 2 + hh];
                aS1[0] = fmaf(m1, cq.x, aS1[0]); aS1[1] = fmaf(m1, cq.y, aS1[1]);
                aS1[2] = fmaf(m1, cq.z, aS1[2]); aS1[3] = fmaf(m1, cq.w, aS1[3]);
                aM1[0] = fmaf(m1, cm.x, aM1[0]); aM1[1] = fmaf(m1, cm.y, aM1[1]);
                aM1[2] = fmaf(m1, cm.z, aM1[2]); aM1[3] = fmaf(m1, cm.w, aM1[3]);
            }
        }
        __syncthreads();   // all combo reads done -> safe to reuse region
        float* scF = combo;          // final sc[h*128+t]
        float* mvF = combo + 1024;   // final mvb[h*128+t]
        float* pS  = combo + 2048;   // chunk-1 partial S
        float* pM  = combo + 3072;   // chunk-1 partial M
        if (c == 1) {
            #pragma unroll
            for (int k = 0; k < 4; ++k) {
                const int h = hh * 4 + k;
                pS[h * NT + t]      = aS1[k];
                pS[h * NT + t + 64] = aS2[k];
                pM[h * NT + t]      = aM1[k];
                pM[h * NT + t + 64] = aM2[k];
            }
        }
        __syncthreads();
        if (c == 0) {
            #pragma unroll
            for (int k = 0; k < 4; ++k) {
                const int h = hh * 4 + k;
                scF[h * NT + t]      = aS1[k] + pS[h * NT + t];
                scF[h * NT + t + 64] = aS2[k] + pS[h * NT + t + 64];
                mvF[h * NT + t]      = aM1[k] + pM[h * NT + t];
                mvF[h * NT + t + 64] = aM2[k] + pM[h * NT + t + 64];
            }
        }
    }
    __syncthreads();

    // ---- Phase F: per-head softmax over t<L, s_h = sum_t p*(mv+vb+evv) ----
    // (Entries t in [L,128) of sc/mvb are finite garbage; masked by lane<L.)
    {
        const float* sc  = combo;
        const float* mvb = combo + 1024;
        const int wv = tid >> 6, lane = tid & 63;
        float wsum = 0.f;
        for (int hh = 0; hh < 2; ++hh) {
            const int h = wv * 2 + hh;
            float s1 = (lane < L) ? sc[h * NT + lane] : -3e38f;
            float s2 = (lane + 64 < L) ? sc[h * NT + 64 + lane] : -3e38f;
            float mx = fmaxf(s1, s2);
            #pragma unroll
            for (int off = 32; off > 0; off >>= 1)
                mx = fmaxf(mx, __shfl_down(mx, off, 64));
            mx = __shfl(mx, 0, 64);
            const float vbv = evvS[h] + cstp[8 + h];
            float e1 = (lane < L) ? __expf(s1 - mx) : 0.f;
            float e2 = (lane + 64 < L) ? __expf(s2 - mx) : 0.f;
            float num = e1 * (mvb[h * NT + lane] + vbv);
            num = fmaf(e2, mvb[h * NT + 64 + lane] + vbv, num);
            float den = e1 + e2;
            #pragma unroll
            for (int off = 32; off > 0; off >>= 1) {
                num += __shfl_down(num, off, 64);
                den += __shfl_down(den, off, 64);
            }
            if (lane == 0) wsum += num / den;
        }
        if (lane == 0) red[wv] = wsum;
    }
    __syncthreads();
    if (tid == 0)
        ws[OFF_S + wg] = cstp[7] + red[0] + red[1] + red[2] + red[3];
}

__global__ __launch_bounds__(64) void final_kernel(
    const float* __restrict__ statics, const int* __restrict__ lengths,
    const float* __restrict__ ws, float* __restrict__ out)
{
    const int b = threadIdx.x;   // 64 threads, one per batch
    const float* s_arr = ws + OFF_S;
    const float* cst = ws + OFF_CST;
    float sum = 0.f;
    int n = 0;
    for (int a = 0; a < NA; ++a) {
        if (lengths[b * NA + a] > 0) { sum += s_arr[b * NA + a]; ++n; }
    }
    float o = sum / ((float)n + 1e-9f);
    #pragma unroll
    for (int i = 0; i < NS; ++i)
        o = fmaf(statics[b * NS + i], cst[i], o);
    o += cst[6];
    out[b] = o;
}

extern "C" void kernel_launch(void* const* d_in, const int* in_sizes, int n_in,
                              void* d_out, int out_size, void* d_ws, size_t ws_size,
                              hipStream_t stream) {
    const float* data     = (const float*)d_in[0];
    // d_in[1] = time  (implied by mask; unused)
    const int*   mask     = (const int*)d_in[2];
    const float* statics  = (const float*)d_in[3];
    const float* W_embed  = (const float*)d_in[4];
    const float* b_embed  = (const float*)d_in[5];
    const float* E_var    = (const float*)d_in[6];
    const float* W_static = (const float*)d_in[7];
    const float* b_static = (const float*)d_in[8];
    const float* Wq       = (const float*)d_in[9];
    const float* bq       = (const float*)d_in[10];
    const float* Wk       = (const float*)d_in[11];
    // d_in[12] = bk (uniform over t -> cancels in softmax; unused)
    const float* Wv       = (const float*)d_in[13];
    const float* bv       = (const float*)d_in[14];
    const float* Wo       = (const float*)d_in[15];
    const float* bo       = (const float*)d_in[16];
    const float* Wg       = (const float*)d_in[17];
    const float* bg       = (const float*)d_in[18];
    float* out = (float*)d_out;
    float* ws  = (float*)d_ws;

    setup_kernel<<<dim3(393), dim3(256), 0, stream>>>(Wk, Wv, Wo, Wg, bv, bo,
                                                      W_static, b_static, bg, ws);
    main_kernel<<<dim3(NB * NA), dim3(256), 0, stream>>>(data, mask, W_embed, b_embed,
                                                         E_var, Wq, bq, ws);
    final_kernel<<<dim3(1), dim3(64), 0, stream>>>(statics, mask, ws, out);
}

// Round 5
// 174.230 us; speedup vs baseline: 1.2318x; 1.0011x over previous
//
#include <hip/hip_runtime.h>
#include <math.h>

// Problem dims
#define NB 64
#define NA 23
#define NT 128
#define ND 256
#define NAE 32
#define NS 6
#define NH 8
#define NDM 288

// Workspace layout (float offsets) — total 134400 floats (537,600 B), fits prior 540,480 B budget.
#define OFF_PEK    0        // PEK[t][j] = sum_e pe[e][t]*Wk[e][j]/sqrt32 : 128*256
#define OFF_PECUM  32768    // PEcum[L-1][e] : 128*256 (inclusive prefix over t)
#define OFF_WKT    65536    // WkT[j][e<256] = Wk[e][j]/sqrt32 : 256*256
#define OFF_VWO    131072   // VWo[h][e<256] : 8*256
#define OFF_PEMV   133120   // PEMV[h][t] = sum_e pe[e][t]*VWo[h][e] : 8*128
#define OFF_EVA    134144   // evvA[a][h] = E_var[a].VWoExt[h] + bv.WoWg[h] : 23*8
#define OFF_CST    134328   // [0..5]=sWf, [6]=b_static.Wg1+bg, [7]=bo.Wg0
#define OFF_SB     134336   // per-b atomic sums : 64

// ---------------- setup1: 393 blocks ----------------
//  [0,128)   : pe prefix scan -> PEcum (2 e-columns per block)
//  [128,384) : WkT transpose, one j-row per block
//  [384,392) : per-head wog, VWo (e<256), vext, evvA[a][h]
//  392       : cst[0..7]
__global__ __launch_bounds__(256) void setup1_kernel(
    const float* __restrict__ Wk, const float* __restrict__ Wv,
    const float* __restrict__ Wo, const float* __restrict__ Wg,
    const float* __restrict__ bv, const float* __restrict__ bo,
    const float* __restrict__ W_static, const float* __restrict__ b_static,
    const float* __restrict__ bg, const float* __restrict__ E_var,
    float* __restrict__ ws)
{
    const int blk = blockIdx.x;
    const int tid = threadIdx.x;
    float* PEcum = ws + OFF_PECUM;
    float* WkT   = ws + OFF_WKT;
    float* VWo   = ws + OFF_VWO;
    float* cst   = ws + OFF_CST;

    if (blk < 128) {
        // pe: e = blk*2 + (tid>>7), t = tid&127. One transcendental per thread.
        const int g = tid >> 7, t = tid & 127;
        const int e = blk * 2 + g;
        const int i = e >> 1;
        const float kdiv = 0.07195578415606394f; // ln(10000)/128
        const float dv = expf(-(float)i * kdiv);
        const float ang = (float)t * dv;
        const float v = (e & 1) ? cosf(ang) : sinf(ang);
        __shared__ float buf[256];
        buf[tid] = v;
        // inclusive Hillis-Steele scan over t within each 128-group
        #pragma unroll
        for (int s = 1; s < 128; s <<= 1) {
            __syncthreads();
            float add = (t >= s) ? buf[tid - s] : 0.f;
            __syncthreads();
            buf[tid] += add;
        }
        __syncthreads();
        PEcum[t * ND + e] = buf[tid];   // row (L-1) holds sum_{t'<L}
    } else if (blk < 384) {
        const int j = blk - 128;
        const float scale = 0.17677669529663687f;
        WkT[j * 256 + tid] = Wk[tid * ND + j] * scale;
    } else if (blk < 392) {
        const int h = blk - 384;
        __shared__ float wog[32];    // WoWg[h*32+jj]
        __shared__ float vext[32];   // VWo rows 256..287
        __shared__ float vbS;
        {
            const int jj = tid >> 3, sub = tid & 7;   // 8 lanes per jj
            const int j = h * 32 + jj;
            float acc = 0.f;
            const int m0 = sub * 36;                  // 288 = 8*36
            #pragma unroll 4
            for (int m = m0; m < m0 + 36; ++m)
                acc = fmaf(Wo[j * NDM + m], Wg[m], acc);
            acc += __shfl_down(acc, 4, 8);
            acc += __shfl_down(acc, 2, 8);
            acc += __shfl_down(acc, 1, 8);
            if (sub == 0) wog[jj] = acc;
        }
        __syncthreads();
        {   // main VWo rows (e<256), one per thread
            float acc = 0.f;
            #pragma unroll 8
            for (int jj = 0; jj < 32; ++jj)
                acc = fmaf(Wv[tid * ND + h * 32 + jj], wog[jj], acc);
            VWo[h * 256 + tid] = acc;
        }
        if (tid < 32) {  // ext rows e = 256+tid
            float acc = 0.f;
            #pragma unroll 8
            for (int jj = 0; jj < 32; ++jj)
                acc = fmaf(Wv[(256 + tid) * ND + h * 32 + jj], wog[jj], acc);
            vext[tid] = acc;
        }
        if (tid == 0) {
            float acc = 0.f;
            #pragma unroll 8
            for (int jj = 0; jj < 32; ++jj)
                acc = fmaf(bv[h * 32 + jj], wog[jj], acc);
            vbS = acc;
        }
        __syncthreads();
        if (tid < NA) {   // evvA[a][h] = vb + E_var[a].vext
            float acc = vbS;
            #pragma unroll 8
            for (int ee = 0; ee < 32; ++ee)
                acc = fmaf(E_var[tid * NAE + ee], vext[ee], acc);
            ws[OFF_EVA + tid * NH + h] = acc;
        }
    } else {
        // cst[0..7]: 32 lanes per output
        const int i = tid >> 5, sub = tid & 31;
        float acc = 0.f;
        if (i < 6) {
            for (int m = sub; m < 256; m += 32)
                acc = fmaf(W_static[i * ND + m], Wg[NDM + m], acc);
        } else if (i == 6) {
            for (int m = sub; m < 256; m += 32)
                acc = fmaf(b_static[m], Wg[NDM + m], acc);
        } else {
            for (int m = sub; m < NDM; m += 32)
                acc = fmaf(bo[m], Wg[m], acc);
        }
        #pragma unroll
        for (int off = 16; off > 0; off >>= 1)
            acc += __shfl_down(acc, off, 32);
        if (sub == 0) cst[i] = (i == 6) ? acc + bg[0] : acc;
    }
}

// ---------------- setup2: 128 blocks (one per t), needs VWo from setup1 ----------------
__global__ __launch_bounds__(256) void setup2_kernel(
    const float* __restrict__ Wk, float* __restrict__ ws)
{
    const int t = blockIdx.x;
    const int tid = threadIdx.x;
    __shared__ float peS[256];
    {
        const int i = tid >> 1;
        const float kdiv = 0.07195578415606394f;
        const float dv = expf(-(float)i * kdiv);
        const float ang = (float)t * dv;
        peS[tid] = (tid & 1) ? cosf(ang) : sinf(ang);
    }
    __syncthreads();
    {   // PEK[t][j] for j = tid (coalesced Wk column reads)
        float a0 = 0.f, a1 = 0.f, a2 = 0.f, a3 = 0.f;
        #pragma unroll 4
        for (int e = 0; e < 256; e += 4) {
            a0 = fmaf(peS[e],     Wk[ e      * ND + tid], a0);
            a1 = fmaf(peS[e + 1], Wk[(e + 1) * ND + tid], a1);
            a2 = fmaf(peS[e + 2], Wk[(e + 2) * ND + tid], a2);
            a3 = fmaf(peS[e + 3], Wk[(e + 3) * ND + tid], a3);
        }
        const float scale = 0.17677669529663687f;
        ws[OFF_PEK + t * 256 + tid] = ((a0 + a1) + (a2 + a3)) * scale;
    }
    {   // PEMV[h][t], 32 lanes per h
        const int h = tid >> 5, ee = tid & 31;
        const float* vw = ws + OFF_VWO + h * 256;
        float v = 0.f;
        #pragma unroll
        for (int k = 0; k < 8; ++k)
            v = fmaf(peS[ee + 32 * k], vw[ee + 32 * k], v);
        v += __shfl_down(v, 16, 32);
        v += __shfl_down(v, 8, 32);
        v += __shfl_down(v, 4, 32);
        v += __shfl_down(v, 2, 32);
        v += __shfl_down(v, 1, 32);
        if (ee == 0) ws[OFF_PEMV + h * NT + t] = v;
    }
    if (t == 0 && tid < NB) ws[OFF_SB + tid] = 0.f;   // reset atomic sums
}

// ---------------- main ----------------
__global__ __launch_bounds__(256) void main_kernel(
    const float* __restrict__ data, const int* __restrict__ lengths,
    const float* __restrict__ W_embed, const float* __restrict__ b_embed,
    const float* __restrict__ E_var,
    const float* __restrict__ Wq, const float* __restrict__ bq,
    float* __restrict__ ws)
{
    const int wg = blockIdx.x;        // b*23 + a
    const int a = wg % NA;
    const int b = wg / NA;
    const int tid = threadIdx.x;
    const int L = lengths[wg];        // wave-uniform

    if (L == 0) return;               // contributes nothing

    __shared__ float xs[NT];
    __shared__ float agentwise[NDM];
    __shared__ __align__(16) float qs[ND];
    __shared__ float2 Wb[ND];
    // combo: row e = 4 float4s {qk h0-3, qk h4-7, VWo h0-3, VWo h4-7},
    // XOR-swizzled at float4 granularity (slot q^(e&3)): round-2-measured
    // 186K conflicts on the b128 stores. Phase-E reads are wave-uniform
    // broadcasts (conflict-free). Dead after E-compute -> aliased sc/mvb/pS/pM.
    __shared__ __align__(16) float combo[ND * 16];
    // qkx: triple duty: Phase-C scratch partials -> per-block pe-score
    // correction qkx[h][t] (written Phase D, read Phase F).
    __shared__ __align__(16) float qkx[NH * NT];
    __shared__ float red[4];

    const float* PEcum = ws + OFF_PECUM;
    const float* WkT   = ws + OFF_WKT;
    const float* VWo   = ws + OFF_VWO;
    const float* cstp  = ws + OFF_CST;

    // ---- Phase A: x row, W/b rows, agentwise via pe prefix table ----
    if (tid < NT) xs[tid] = data[wg * NT + tid];
    __syncthreads();
    {
        const int e = tid;   // 0..255
        const float We = W_embed[a * ND + e];
        const float be = b_embed[a * ND + e];
        Wb[e] = make_float2(We, be);
        float s0 = 0.f, s1 = 0.f, s2 = 0.f, s3 = 0.f;
        int t = 0;
        for (; t + 4 <= L; t += 4) {
            s0 += fmaxf(fmaf(xs[t],     We, be), 0.f);
            s1 += fmaxf(fmaf(xs[t + 1], We, be), 0.f);
            s2 += fmaxf(fmaf(xs[t + 2], We, be), 0.f);
            s3 += fmaxf(fmaf(xs[t + 3], We, be), 0.f);
        }
        for (; t < L; ++t)
            s0 += fmaxf(fmaf(xs[t], We, be), 0.f);
        agentwise[e] = (((s0 + s1) + (s2 + s3)) + PEcum[(L - 1) * ND + e]) / (float)L;
    }
    if (tid < NAE) agentwise[ND + tid] = E_var[a * NAE + tid];
    __syncthreads();

    // ---- Phase C: q[j] = agentwise . Wq[:,j] + bq[j] ----
    // 4 consecutive j per thread via coalesced float4 Wq loads over a
    // wave-uniform 72-f chunk; partials into qkx scratch, reduced into qs.
    {
        const int lane = tid & 63;
        const int fc = tid >> 6;            // wave-uniform
        const float4* Wq4 = (const float4*)Wq;
        float a0 = 0.f, a1 = 0.f, a2 = 0.f, a3 = 0.f;
        const int f0 = fc * 72;
        #pragma unroll 4
        for (int f = f0; f < f0 + 72; ++f) {
            const float ag = agentwise[f];          // LDS broadcast
            const float4 w = Wq4[f * 64 + lane];    // coalesced 16B/lane
            a0 = fmaf(ag, w.x, a0);
            a1 = fmaf(ag, w.y, a1);
            a2 = fmaf(ag, w.z, a2);
            a3 = fmaf(ag, w.w, a3);
        }
        ((float4*)qkx)[fc * 64 + lane] = make_float4(a0, a1, a2, a3);
    }
    __syncthreads();
    qs[tid] = bq[tid] + qkx[tid] + qkx[256 + tid] + qkx[512 + tid] + qkx[768 + tid];
    __syncthreads();

    // ---- Phase D: thread e owns combo row e (8 qk dots + 8 VWo), plus the
    // per-block pe-score correction qkx[h][t] from the precomputed PEK table.
    {
        const int e = tid;
        const float* wcol = WkT + e;      // WkT[j*256+e], lane-coalesced
        const int r = e & 3;
        float4* row = (float4*)combo + e * 4;
        float qk[8];
        #pragma unroll
        for (int h = 0; h < 8; ++h) {
            const float* wr = wcol + (h * 32) * 256;
            const float* qh = qs + h * 32;
            float c0 = 0.f, c1 = 0.f;
            #pragma unroll
            for (int j = 0; j < 32; j += 2) {
                c0 = fmaf(wr[ j      * 256], qh[j],     c0);
                c1 = fmaf(wr[(j + 1) * 256], qh[j + 1], c1);
            }
            qk[h] = c0 + c1;
        }
        row[0 ^ r] = make_float4(qk[0], qk[1], qk[2], qk[3]);
        row[1 ^ r] = make_float4(qk[4], qk[5], qk[6], qk[7]);
        row[2 ^ r] = make_float4(VWo[0 * 256 + e], VWo[1 * 256 + e],
                                 VWo[2 * 256 + e], VWo[3 * 256 + e]);
        row[3 ^ r] = make_float4(VWo[4 * 256 + e], VWo[5 * 256 + e],
                                 VWo[6 * 256 + e], VWo[7 * 256 + e]);
    }
    __syncthreads();   // qkx scratch fully consumed (qs done) -> D can overwrite
    {
        // qkx[h][t] = sum_{j in head h} qs[h*32+j] * PEK[t][h*32+j]
        const int h = tid >> 5, t0 = tid & 31;
        const float4* qs4  = (const float4*)qs;
        const float4* PEK4 = (const float4*)(ws + OFF_PEK);
        #pragma unroll
        for (int tt = 0; tt < 4; ++tt) {
            const int t = t0 + tt * 32;
            const float4* pk = PEK4 + t * 64 + h * 8;
            float b0 = 0.f, b1 = 0.f, b2 = 0.f, b3 = 0.f;
            #pragma unroll
            for (int jq = 0; jq < 8; ++jq) {
                const float4 q = qs4[h * 8 + jq];   // broadcast
                const float4 p = pk[jq];
                b0 = fmaf(q.x, p.x, b0);
                b1 = fmaf(q.y, p.y, b1);
                b2 = fmaf(q.z, p.z, b2);
                b3 = fmaf(q.w, p.w, b3);
            }
            qkx[h * NT + t] = (b0 + b1) + (b2 + b3);
        }
    }
    __syncthreads();

    // ---- Phase E: h-split + t-pair; NO global loads in the hot loop ----
    {
        const int t  = tid & 63;
        const int hh = (tid >> 6) & 1;   // wave-uniform
        const int c  = tid >> 7;         // wave-uniform
        const int ebase = c * 128;
        const float xt1 = xs[t];
        const float xt2 = xs[t + 64];
        const float4* comboV = (const float4*)combo;
        float aS1[4], aS2[4], aM1[4], aM2[4];
        #pragma unroll
        for (int k = 0; k < 4; ++k) { aS1[k] = 0.f; aS2[k] = 0.f; aM1[k] = 0.f; aM2[k] = 0.f; }

        if (L > 64) {
            #pragma unroll 4
            for (int ee = 0; ee < 128; ++ee) {
                const int e = ebase + ee;
                const int r = e & 3;
                const float2 wb = Wb[e];
                const float m1 = fmaxf(fmaf(xt1, wb.x, wb.y), 0.f);
                const float m2 = fmaxf(fmaf(xt2, wb.x, wb.y), 0.f);
                const float4 cq = comboV[e * 4 + (hh ^ r)];        // qk quad
                const float4 cm = comboV[e * 4 + ((2 | hh) ^ r)];  // VWo quad
                aS1[0] = fmaf(m1, cq.x, aS1[0]); aS1[1] = fmaf(m1, cq.y, aS1[1]);
                aS1[2] = fmaf(m1, cq.z, aS1[2]); aS1[3] = fmaf(m1, cq.w, aS1[3]);
                aS2[0] = fmaf(m2, cq.x, aS2[0]); aS2[1] = fmaf(m2, cq.y, aS2[1]);
                aS2[2] = fmaf(m2, cq.z, aS2[2]); aS2[3] = fmaf(m2, cq.w, aS2[3]);
                aM1[0] = fmaf(m1, cm.x, aM1[0]); aM1[1] = fmaf(m1, cm.y, aM1[1]);
                aM1[2] = fmaf(m1, cm.z, aM1[2]); aM1[3] = fmaf(m1, cm.w, aM1[3]);
                aM2[0] = fmaf(m2, cm.x, aM2[0]); aM2[1] = fmaf(m2, cm.y, aM2[1]);
                aM2[2] = fmaf(m2, cm.z, aM2[2]); aM2[3] = fmaf(m2, cm.w, aM2[3]);
            }
        } else {
            // t+64 >= L always masked in Phase F -> skip second-t work.
            #pragma unroll 4
            for (int ee = 0; ee < 128; ++ee) {
                const int e = ebase + ee;
                const int r = e & 3;
                const float2 wb = Wb[e];
                const float m1 = fmaxf(fmaf(xt1, wb.x, wb.y), 0.f);
                const float4 cq = comboV[e * 4 + (hh ^ r)];
                const float4 cm = comboV[e * 4 + ((2 | hh) ^ r)];
                aS1[0] = fmaf(m1, cq.x, aS1[0]); aS1[1] = fmaf(m1, cq.y, aS1[1]);
                aS1[2] = fmaf(m1, cq.z, aS1[2]); aS1[3] = fmaf(m1, cq.w, aS1[3]);
                aM1[0] = fmaf(m1, cm.x, aM1[0]); aM1[1] = fmaf(m1, cm.y, aM1[1]);
                aM1[2] = fmaf(m1, cm.z, aM1[2]); aM1[3] = fmaf(m1, cm.w, aM1[3]);
            }
        }
        __syncthreads();   // all combo reads done -> reuse region
        float* scF = combo;          // sc[h*128+t]
        float* mvF = combo + 1024;   // mvb[h*128+t]
        float* pS  = combo + 2048;   // chunk-1 partial S
        float* pM  = combo + 3072;   // chunk-1 partial M
        if (c == 1) {
            #pragma unroll
            for (int k = 0; k < 4; ++k) {
                const int h = hh * 4 + k;
                pS[h * NT + t]      = aS1[k];
                pS[h * NT + t + 64] = aS2[k];
                pM[h * NT + t]      = aM1[k];
                pM[h * NT + t + 64] = aM2[k];
            }
        }
        __syncthreads();
        if (c == 0) {
            #pragma unroll
            for (int k = 0; k < 4; ++k) {
                const int h = hh * 4 + k;
                scF[h * NT + t]      = aS1[k] + pS[h * NT + t];
                scF[h * NT + t + 64] = aS2[k] + pS[h * NT + t + 64];
                mvF[h * NT + t]      = aM1[k] + pM[h * NT + t];
                mvF[h * NT + t + 64] = aM2[k] + pM[h * NT + t + 64];
            }
        }
    }
    __syncthreads();

    // ---- Phase F: per-head softmax over t<L; score/mv corrections added here ----
    {
        const float* sc   = combo;
        const float* mvb  = combo + 1024;
        const float* pemv = ws + OFF_PEMV;
        const int wv = tid >> 6, lane = tid & 63;
        float wsum = 0.f;
        for (int hh = 0; hh < 2; ++hh) {
            const int h = wv * 2 + hh;
            float s1 = (lane < L) ? sc[h * NT + lane] + qkx[h * NT + lane] : -3e38f;
            float s2 = (lane + 64 < L) ? sc[h * NT + 64 + lane] + qkx[h * NT + 64 + lane] : -3e38f;
            float mx = fmaxf(s1, s2);
            #pragma unroll
            for (int off = 32; off > 0; off >>= 1)
                mx = fmaxf(mx, __shfl_down(mx, off, 64));
            mx = __shfl(mx, 0, 64);
            const float vbv = ws[OFF_EVA + a * NH + h];
            float e1 = (lane < L) ? __expf(s1 - mx) : 0.f;
            float e2 = (lane + 64 < L) ? __expf(s2 - mx) : 0.f;
            float num = e1 * (mvb[h * NT + lane] + pemv[h * NT + lane] + vbv);
            num = fmaf(e2, mvb[h * NT + 64 + lane] + pemv[h * NT + 64 + lane] + vbv, num);
            float den = e1 + e2;
            #pragma unroll
            for (int off = 32; off > 0; off >>= 1) {
                num += __shfl_down(num, off, 64);
                den += __shfl_down(den, off, 64);
            }
            if (lane == 0) wsum += num / den;
        }
        if (lane == 0) red[wv] = wsum;
    }
    __syncthreads();
    if (tid == 0)
        atomicAdd(ws + OFF_SB + b, cstp[7] + red[0] + red[1] + red[2] + red[3]);
}

__global__ __launch_bounds__(64) void final_kernel(
    const float* __restrict__ statics, const int* __restrict__ lengths,
    const float* __restrict__ ws, float* __restrict__ out)
{
    const int b = threadIdx.x;   // 64 threads, one per batch
    const float* cst = ws + OFF_CST;
    int n = 0;
    for (int a = 0; a < NA; ++a)
        if (lengths[b * NA + a] > 0) ++n;
    float o = ws[OFF_SB + b] / ((float)n + 1e-9f);
    #pragma unroll
    for (int i = 0; i < NS; ++i)
        o = fmaf(statics[b * NS + i], cst[i], o);
    o += cst[6];
    out[b] = o;
}

extern "C" void kernel_launch(void* const* d_in, const int* in_sizes, int n_in,
                              void* d_out, int out_size, void* d_ws, size_t ws_size,
                              hipStream_t stream) {
    const float* data     = (const float*)d_in[0];
    // d_in[1] = time  (implied by mask; unused)
    const int*   mask     = (const int*)d_in[2];
    const float* statics  = (const float*)d_in[3];
    const float* W_embed  = (const float*)d_in[4];
    const float* b_embed  = (const float*)d_in[5];
    const float* E_var    = (const float*)d_in[6];
    const float* W_static = (const float*)d_in[7];
    const float* b_static = (const float*)d_in[8];
    const float* Wq       = (const float*)d_in[9];
    const float* bq       = (const float*)d_in[10];
    const float* Wk       = (const float*)d_in[11];
    // d_in[12] = bk (uniform over t -> cancels in softmax; unused)
    const float* Wv       = (const float*)d_in[13];
    const float* bv       = (const float*)d_in[14];
    const float* Wo       = (const float*)d_in[15];
    const float* bo       = (const float*)d_in[16];
    const float* Wg       = (const float*)d_in[17];
    const float* bg       = (const float*)d_in[18];
    float* out = (float*)d_out;
    float* ws  = (float*)d_ws;

    setup1_kernel<<<dim3(393), dim3(256), 0, stream>>>(Wk, Wv, Wo, Wg, bv, bo,
                                                       W_static, b_static, bg, E_var, ws);
    setup2_kernel<<<dim3(128), dim3(256), 0, stream>>>(Wk, ws);
    main_kernel<<<dim3(NB * NA), dim3(256), 0, stream>>>(data, mask, W_embed, b_embed,
                                                         E_var, Wq, bq, ws);
    final_kernel<<<dim3(1), dim3(64), 0, stream>>>(statics, mask, ws, out);
}

// Round 6
// 173.619 us; speedup vs baseline: 1.2361x; 1.0035x over previous
//
#include <hip/hip_runtime.h>
#include <math.h>

// Problem dims
#define NB 64
#define NA 23
#define NT 128
#define ND 256
#define NAE 32
#define NS 6
#define NH 8
#define NDM 288

// Workspace layout (float offsets) — total 134400 floats (537,600 B).
#define OFF_PEK    0        // PEK[t][j] = sum_e pe[e][t]*Wk[e][j]/sqrt32 : 128*256
#define OFF_PECUM  32768    // PEcum[L-1][e] : 128*256 (inclusive prefix over t)
#define OFF_WKT    65536    // WkT[j][e<256] = Wk[e][j]/sqrt32 : 256*256
#define OFF_VWO    131072   // VWo[h][e<256] : 8*256
#define OFF_PEMV   133120   // PEMV[h][t] = sum_e pe[e][t]*VWo[h][e] : 8*128
#define OFF_EVA    134144   // evvA[a][h] = E_var[a].VWoExt[h] + bv.WoWg[h] : 23*8
#define OFF_CST    134328   // [0..5]=sWf, [6]=b_static.Wg1+bg, [7]=bo.Wg0
#define OFF_SB     134336   // per-b atomic sums : 64

// ---------------- setup1: 393 blocks ----------------
__global__ __launch_bounds__(256) void setup1_kernel(
    const float* __restrict__ Wk, const float* __restrict__ Wv,
    const float* __restrict__ Wo, const float* __restrict__ Wg,
    const float* __restrict__ bv, const float* __restrict__ bo,
    const float* __restrict__ W_static, const float* __restrict__ b_static,
    const float* __restrict__ bg, const float* __restrict__ E_var,
    float* __restrict__ ws)
{
    const int blk = blockIdx.x;
    const int tid = threadIdx.x;
    float* PEcum = ws + OFF_PECUM;
    float* WkT   = ws + OFF_WKT;
    float* VWo   = ws + OFF_VWO;
    float* cst   = ws + OFF_CST;

    if (blk < 128) {
        const int g = tid >> 7, t = tid & 127;
        const int e = blk * 2 + g;
        const int i = e >> 1;
        const float kdiv = 0.07195578415606394f; // ln(10000)/128
        const float dv = expf(-(float)i * kdiv);
        const float ang = (float)t * dv;
        const float v = (e & 1) ? cosf(ang) : sinf(ang);
        __shared__ float buf[256];
        buf[tid] = v;
        #pragma unroll
        for (int s = 1; s < 128; s <<= 1) {
            __syncthreads();
            float add = (t >= s) ? buf[tid - s] : 0.f;
            __syncthreads();
            buf[tid] += add;
        }
        __syncthreads();
        PEcum[t * ND + e] = buf[tid];   // row (L-1) holds sum_{t'<L}
    } else if (blk < 384) {
        const int j = blk - 128;
        const float scale = 0.17677669529663687f;
        WkT[j * 256 + tid] = Wk[tid * ND + j] * scale;
    } else if (blk < 392) {
        const int h = blk - 384;
        __shared__ float wog[32];    // WoWg[h*32+jj]
        __shared__ float vext[32];   // VWo rows 256..287
        __shared__ float vbS;
        {
            const int jj = tid >> 3, sub = tid & 7;
            const int j = h * 32 + jj;
            float acc = 0.f;
            const int m0 = sub * 36;
            #pragma unroll 4
            for (int m = m0; m < m0 + 36; ++m)
                acc = fmaf(Wo[j * NDM + m], Wg[m], acc);
            acc += __shfl_down(acc, 4, 8);
            acc += __shfl_down(acc, 2, 8);
            acc += __shfl_down(acc, 1, 8);
            if (sub == 0) wog[jj] = acc;
        }
        __syncthreads();
        {
            float acc = 0.f;
            #pragma unroll 8
            for (int jj = 0; jj < 32; ++jj)
                acc = fmaf(Wv[tid * ND + h * 32 + jj], wog[jj], acc);
            VWo[h * 256 + tid] = acc;
        }
        if (tid < 32) {
            float acc = 0.f;
            #pragma unroll 8
            for (int jj = 0; jj < 32; ++jj)
                acc = fmaf(Wv[(256 + tid) * ND + h * 32 + jj], wog[jj], acc);
            vext[tid] = acc;
        }
        if (tid == 0) {
            float acc = 0.f;
            #pragma unroll 8
            for (int jj = 0; jj < 32; ++jj)
                acc = fmaf(bv[h * 32 + jj], wog[jj], acc);
            vbS = acc;
        }
        __syncthreads();
        if (tid < NA) {
            float acc = vbS;
            #pragma unroll 8
            for (int ee = 0; ee < 32; ++ee)
                acc = fmaf(E_var[tid * NAE + ee], vext[ee], acc);
            ws[OFF_EVA + tid * NH + h] = acc;
        }
    } else {
        const int i = tid >> 5, sub = tid & 31;
        float acc = 0.f;
        if (i < 6) {
            for (int m = sub; m < 256; m += 32)
                acc = fmaf(W_static[i * ND + m], Wg[NDM + m], acc);
        } else if (i == 6) {
            for (int m = sub; m < 256; m += 32)
                acc = fmaf(b_static[m], Wg[NDM + m], acc);
        } else {
            for (int m = sub; m < NDM; m += 32)
                acc = fmaf(bo[m], Wg[m], acc);
        }
        #pragma unroll
        for (int off = 16; off > 0; off >>= 1)
            acc += __shfl_down(acc, off, 32);
        if (sub == 0) cst[i] = (i == 6) ? acc + bg[0] : acc;
    }
}

// ---------------- setup2: 128 blocks (one per t), needs VWo from setup1 ----------------
__global__ __launch_bounds__(256) void setup2_kernel(
    const float* __restrict__ Wk, float* __restrict__ ws)
{
    const int t = blockIdx.x;
    const int tid = threadIdx.x;
    __shared__ float peS[256];
    {
        const int i = tid >> 1;
        const float kdiv = 0.07195578415606394f;
        const float dv = expf(-(float)i * kdiv);
        const float ang = (float)t * dv;
        peS[tid] = (tid & 1) ? cosf(ang) : sinf(ang);
    }
    __syncthreads();
    {
        float a0 = 0.f, a1 = 0.f, a2 = 0.f, a3 = 0.f;
        #pragma unroll 4
        for (int e = 0; e < 256; e += 4) {
            a0 = fmaf(peS[e],     Wk[ e      * ND + tid], a0);
            a1 = fmaf(peS[e + 1], Wk[(e + 1) * ND + tid], a1);
            a2 = fmaf(peS[e + 2], Wk[(e + 2) * ND + tid], a2);
            a3 = fmaf(peS[e + 3], Wk[(e + 3) * ND + tid], a3);
        }
        const float scale = 0.17677669529663687f;
        ws[OFF_PEK + t * 256 + tid] = ((a0 + a1) + (a2 + a3)) * scale;
    }
    {
        const int h = tid >> 5, ee = tid & 31;
        const float* vw = ws + OFF_VWO + h * 256;
        float v = 0.f;
        #pragma unroll
        for (int k = 0; k < 8; ++k)
            v = fmaf(peS[ee + 32 * k], vw[ee + 32 * k], v);
        v += __shfl_down(v, 16, 32);
        v += __shfl_down(v, 8, 32);
        v += __shfl_down(v, 4, 32);
        v += __shfl_down(v, 2, 32);
        v += __shfl_down(v, 1, 32);
        if (ee == 0) ws[OFF_PEMV + h * NT + t] = v;
    }
    if (t == 0 && tid < NB) ws[OFF_SB + tid] = 0.f;   // reset atomic sums
}

// ---------------- main: one block = TWO wg's (weight streams shared) ----------------
// 512 threads. half = tid>>8 owns wg = pair*2+half for phases A/E/F.
// Phases C/D/qkx: every weight element loaded once, fma'd against BOTH agents.
__global__ __launch_bounds__(512) void main_kernel(
    const float* __restrict__ data, const int* __restrict__ lengths,
    const float* __restrict__ W_embed, const float* __restrict__ b_embed,
    const float* __restrict__ E_var,
    const float* __restrict__ Wq, const float* __restrict__ bq,
    float* __restrict__ ws)
{
    const int pair = blockIdx.x;          // 736 pairs
    const int tid  = threadIdx.x;         // 0..511
    const int half = tid >> 8;            // which wg this thread's A/E/F work belongs to
    const int lt   = tid & 255;
    const int wgh  = pair * 2 + half;
    const int ah   = wgh % NA;
    const int bh   = wgh / NA;
    const int Lh   = lengths[wgh];        // uniform across the half's 4 waves

    __shared__ float xs[2][NT];
    __shared__ float ag[2][NDM];
    __shared__ __align__(16) float qs[2][ND];
    __shared__ float2 Wb[2][ND];
    // combo[w]: row e = 4 float4s {qk h0-3, qk h4-7, VWo h0-3, VWo h4-7},
    // XOR-swizzled (slot q^(e&3)) — r2/r5-measured 186K conflicts.
    // First 1024 floats of combo[0] double as Phase-C scratch (barrier-separated).
    __shared__ __align__(16) float combo[2][ND * 16];
    __shared__ __align__(16) float qkx[2][NH * NT];
    __shared__ float red[2][4];

    const float* PEcum = ws + OFF_PECUM;
    const float* WkT   = ws + OFF_WKT;
    const float* VWo   = ws + OFF_VWO;
    const float* cstp  = ws + OFF_CST;

    // ---- Phase A (per half) ----
    if (lt < NT) xs[half][lt] = data[wgh * NT + lt];
    __syncthreads();
    {
        const int e = lt;
        if (Lh > 0) {
            const float We = W_embed[ah * ND + e];
            const float be = b_embed[ah * ND + e];
            Wb[half][e] = make_float2(We, be);
            float s0 = 0.f, s1 = 0.f, s2 = 0.f, s3 = 0.f;
            int t = 0;
            for (; t + 4 <= Lh; t += 4) {
                s0 += fmaxf(fmaf(xs[half][t],     We, be), 0.f);
                s1 += fmaxf(fmaf(xs[half][t + 1], We, be), 0.f);
                s2 += fmaxf(fmaf(xs[half][t + 2], We, be), 0.f);
                s3 += fmaxf(fmaf(xs[half][t + 3], We, be), 0.f);
            }
            for (; t < Lh; ++t)
                s0 += fmaxf(fmaf(xs[half][t], We, be), 0.f);
            ag[half][e] = (((s0 + s1) + (s2 + s3)) + PEcum[(Lh - 1) * ND + e]) / (float)Lh;
        } else {
            Wb[half][e] = make_float2(0.f, 0.f);
            ag[half][e] = 0.f;
        }
    }
    if (lt < NAE) ag[half][ND + lt] = (Lh > 0) ? E_var[ah * NAE + lt] : 0.f;
    __syncthreads();

    // ---- Phase C: q0,q1 — Wq column j read ONCE, fma vs both agents ----
    {
        const int j = lt;
        const int f0 = half * 144;           // 288 = 2 x 144 f-chunks
        float a0 = 0.f, a1 = 0.f, a2 = 0.f, a3 = 0.f;
        #pragma unroll 4
        for (int f = f0; f < f0 + 144; f += 2) {
            const float w0 = Wq[f * ND + j];          // coalesced across j
            const float w1 = Wq[(f + 1) * ND + j];
            a0 = fmaf(ag[0][f],     w0, a0);
            a2 = fmaf(ag[0][f + 1], w1, a2);
            a1 = fmaf(ag[1][f],     w0, a1);
            a3 = fmaf(ag[1][f + 1], w1, a3);
        }
        float* Csc = &combo[0][0];           // scratch[fc][wg][j]
        Csc[half * 512 +       j] = a0 + a2;
        Csc[half * 512 + 256 + j] = a1 + a3;
    }
    __syncthreads();
    {
        const float* Csc = &combo[0][0];
        qs[half][lt] = bq[lt] + Csc[half * 256 + lt] + Csc[512 + half * 256 + lt];
    }
    __syncthreads();

    // ---- Phase D: thread (e, head-half hb) computes qk for 4 heads x BOTH wgs.
    // WkT row read once per pair (was once per wg). Stores use proven r5 swizzle.
    {
        const int e = lt;
        const int hb = half;                 // heads hb*4 .. hb*4+3
        const float* wr = WkT + (hb * 128) * 256 + e;   // lane-coalesced columns
        float qk0[4], qk1[4];
        #pragma unroll
        for (int h4 = 0; h4 < 4; ++h4) {
            const float* q0 = qs[0] + hb * 128 + h4 * 32;
            const float* q1 = qs[1] + hb * 128 + h4 * 32;
            float c00 = 0.f, c01 = 0.f, c10 = 0.f, c11 = 0.f;
            #pragma unroll
            for (int jj = 0; jj < 32; jj += 2) {
                const float wa = wr[(h4 * 32 + jj)     * 256];
                const float wb = wr[(h4 * 32 + jj + 1) * 256];
                c00 = fmaf(wa, q0[jj],     c00);
                c01 = fmaf(wb, q0[jj + 1], c01);
                c10 = fmaf(wa, q1[jj],     c10);
                c11 = fmaf(wb, q1[jj + 1], c11);
            }
            qk0[h4] = c00 + c01;
            qk1[h4] = c10 + c11;
        }
        const int r = e & 3;
        float4* row0 = (float4*)(&combo[0][0]) + e * 4;
        float4* row1 = (float4*)(&combo[1][0]) + e * 4;
        row0[hb ^ r] = make_float4(qk0[0], qk0[1], qk0[2], qk0[3]);
        row1[hb ^ r] = make_float4(qk1[0], qk1[1], qk1[2], qk1[3]);
        const float4 vw = make_float4(VWo[(hb * 4 + 0) * 256 + e],
                                      VWo[(hb * 4 + 1) * 256 + e],
                                      VWo[(hb * 4 + 2) * 256 + e],
                                      VWo[(hb * 4 + 3) * 256 + e]);
        row0[(2 | hb) ^ r] = vw;
        row1[(2 | hb) ^ r] = vw;
    }
    // ---- qkx[wg][h][t] from PEK: each float4 read once, fma vs both wgs ----
    {
        const int h = tid >> 6;              // 0..7
        const int tq = tid & 63;
        const float4* qs40 = (const float4*)qs[0] + h * 8;
        const float4* qs41 = (const float4*)qs[1] + h * 8;
        const float4* PEK4 = (const float4*)(ws + OFF_PEK);
        #pragma unroll
        for (int tt = 0; tt < 2; ++tt) {
            const int t = tq + tt * 64;
            const float4* pk = PEK4 + t * 64 + h * 8;
            float b00 = 0.f, b01 = 0.f, b02 = 0.f, b03 = 0.f;
            float b10 = 0.f, b11 = 0.f, b12 = 0.f, b13 = 0.f;
            #pragma unroll
            for (int jq = 0; jq < 8; ++jq) {
                const float4 p = pk[jq];
                const float4 q0 = qs40[jq];
                const float4 q1 = qs41[jq];
                b00 = fmaf(q0.x, p.x, b00); b01 = fmaf(q0.y, p.y, b01);
                b02 = fmaf(q0.z, p.z, b02); b03 = fmaf(q0.w, p.w, b03);
                b10 = fmaf(q1.x, p.x, b10); b11 = fmaf(q1.y, p.y, b11);
                b12 = fmaf(q1.z, p.z, b12); b13 = fmaf(q1.w, p.w, b13);
            }
            qkx[0][h * NT + t] = (b00 + b01) + (b02 + b03);
            qkx[1][h * NT + t] = (b10 + b11) + (b12 + b13);
        }
    }
    __syncthreads();

    // ---- Phase E (per half; r5 structure verbatim): no global loads ----
    {
        const int t  = lt & 63;
        const int hh = (lt >> 6) & 1;
        const int c  = lt >> 7;
        const int ebase = c * 128;
        const float xt1 = xs[half][t];
        const float xt2 = xs[half][t + 64];
        const float4* comboV = (const float4*)(&combo[half][0]);
        float aS1[4], aS2[4], aM1[4], aM2[4];
        #pragma unroll
        for (int k = 0; k < 4; ++k) { aS1[k] = 0.f; aS2[k] = 0.f; aM1[k] = 0.f; aM2[k] = 0.f; }

        if (Lh > 64) {
            #pragma unroll 4
            for (int ee = 0; ee < 128; ++ee) {
                const int e = ebase + ee;
                const int r = e & 3;
                const float2 wb = Wb[half][e];
                const float m1 = fmaxf(fmaf(xt1, wb.x, wb.y), 0.f);
                const float m2 = fmaxf(fmaf(xt2, wb.x, wb.y), 0.f);
                const float4 cq = comboV[e * 4 + (hh ^ r)];
                const float4 cm = comboV[e * 4 + ((2 | hh) ^ r)];
                aS1[0] = fmaf(m1, cq.x, aS1[0]); aS1[1] = fmaf(m1, cq.y, aS1[1]);
                aS1[2] = fmaf(m1, cq.z, aS1[2]); aS1[3] = fmaf(m1, cq.w, aS1[3]);
                aS2[0] = fmaf(m2, cq.x, aS2[0]); aS2[1] = fmaf(m2, cq.y, aS2[1]);
                aS2[2] = fmaf(m2, cq.z, aS2[2]); aS2[3] = fmaf(m2, cq.w, aS2[3]);
                aM1[0] = fmaf(m1, cm.x, aM1[0]); aM1[1] = fmaf(m1, cm.y, aM1[1]);
                aM1[2] = fmaf(m1, cm.z, aM1[2]); aM1[3] = fmaf(m1, cm.w, aM1[3]);
                aM2[0] = fmaf(m2, cm.x, aM2[0]); aM2[1] = fmaf(m2, cm.y, aM2[1]);
                aM2[2] = fmaf(m2, cm.z, aM2[2]); aM2[3] = fmaf(m2, cm.w, aM2[3]);
            }
        } else if (Lh > 0) {
            // t+64 >= L always masked in Phase F -> skip second-t work.
            #pragma unroll 4
            for (int ee = 0; ee < 128; ++ee) {
                const int e = ebase + ee;
                const int r = e & 3;
                const float2 wb = Wb[half][e];
                const float m1 = fmaxf(fmaf(xt1, wb.x, wb.y), 0.f);
                const float4 cq = comboV[e * 4 + (hh ^ r)];
                const float4 cm = comboV[e * 4 + ((2 | hh) ^ r)];
                aS1[0] = fmaf(m1, cq.x, aS1[0]); aS1[1] = fmaf(m1, cq.y, aS1[1]);
                aS1[2] = fmaf(m1, cq.z, aS1[2]); aS1[3] = fmaf(m1, cq.w, aS1[3]);
                aM1[0] = fmaf(m1, cm.x, aM1[0]); aM1[1] = fmaf(m1, cm.y, aM1[1]);
                aM1[2] = fmaf(m1, cm.z, aM1[2]); aM1[3] = fmaf(m1, cm.w, aM1[3]);
            }
        }
        __syncthreads();   // all combo reads done -> reuse region
        float* scF = &combo[half][0];        // sc[h*128+t]
        float* mvF = scF + 1024;             // mvb[h*128+t]
        float* pS  = scF + 2048;             // chunk-1 partial S
        float* pM  = scF + 3072;             // chunk-1 partial M
        if (c == 1) {
            #pragma unroll
            for (int k = 0; k < 4; ++k) {
                const int h = hh * 4 + k;
                pS[h * NT + t]      = aS1[k];
                pS[h * NT + t + 64] = aS2[k];
                pM[h * NT + t]      = aM1[k];
                pM[h * NT + t + 64] = aM2[k];
            }
        }
        __syncthreads();
        if (c == 0) {
            #pragma unroll
            for (int k = 0; k < 4; ++k) {
                const int h = hh * 4 + k;
                scF[h * NT + t]      = aS1[k] + pS[h * NT + t];
                scF[h * NT + t + 64] = aS2[k] + pS[h * NT + t + 64];
                mvF[h * NT + t]      = aM1[k] + pM[h * NT + t];
                mvF[h * NT + t + 64] = aM2[k] + pM[h * NT + t + 64];
            }
        }
    }
    __syncthreads();

    // ---- Phase F (per half): softmax over t<Lh with pe corrections ----
    if (Lh > 0) {
        const float* sc   = &combo[half][0];
        const float* mvb  = sc + 1024;
        const float* pemv = ws + OFF_PEMV;
        const int wv = lt >> 6, lane = lt & 63;
        float wsum = 0.f;
        for (int hh2 = 0; hh2 < 2; ++hh2) {
            const int h = wv * 2 + hh2;
            float s1 = (lane < Lh) ? sc[h * NT + lane] + qkx[half][h * NT + lane] : -3e38f;
            float s2 = (lane + 64 < Lh) ? sc[h * NT + 64 + lane] + qkx[half][h * NT + 64 + lane] : -3e38f;
            float mx = fmaxf(s1, s2);
            #pragma unroll
            for (int off = 32; off > 0; off >>= 1)
                mx = fmaxf(mx, __shfl_down(mx, off, 64));
            mx = __shfl(mx, 0, 64);
            const float vbv = ws[OFF_EVA + ah * NH + h];
            float e1 = (lane < Lh) ? __expf(s1 - mx) : 0.f;
            float e2 = (lane + 64 < Lh) ? __expf(s2 - mx) : 0.f;
            float num = e1 * (mvb[h * NT + lane] + pemv[h * NT + lane] + vbv);
            num = fmaf(e2, mvb[h * NT + 64 + lane] + pemv[h * NT + 64 + lane] + vbv, num);
            float den = e1 + e2;
            #pragma unroll
            for (int off = 32; off > 0; off >>= 1) {
                num += __shfl_down(num, off, 64);
                den += __shfl_down(den, off, 64);
            }
            if (lane == 0) wsum += num / den;
        }
        if (lane == 0) red[half][wv] = wsum;
    }
    __syncthreads();
    if (lt == 0 && Lh > 0)
        atomicAdd(ws + OFF_SB + bh,
                  cstp[7] + red[half][0] + red[half][1] + red[half][2] + red[half][3]);
}

__global__ __launch_bounds__(64) void final_kernel(
    const float* __restrict__ statics, const int* __restrict__ lengths,
    const float* __restrict__ ws, float* __restrict__ out)
{
    const int b = threadIdx.x;   // 64 threads, one per batch
    const float* cst = ws + OFF_CST;
    int n = 0;
    for (int a = 0; a < NA; ++a)
        if (lengths[b * NA + a] > 0) ++n;
    float o = ws[OFF_SB + b] / ((float)n + 1e-9f);
    #pragma unroll
    for (int i = 0; i < NS; ++i)
        o = fmaf(statics[b * NS + i], cst[i], o);
    o += cst[6];
    out[b] = o;
}

extern "C" void kernel_launch(void* const* d_in, const int* in_sizes, int n_in,
                              void* d_out, int out_size, void* d_ws, size_t ws_size,
                              hipStream_t stream) {
    const float* data     = (const float*)d_in[0];
    // d_in[1] = time  (implied by mask; unused)
    const int*   mask     = (const int*)d_in[2];
    const float* statics  = (const float*)d_in[3];
    const float* W_embed  = (const float*)d_in[4];
    const float* b_embed  = (const float*)d_in[5];
    const float* E_var    = (const float*)d_in[6];
    const float* W_static = (const float*)d_in[7];
    const float* b_static = (const float*)d_in[8];
    const float* Wq       = (const float*)d_in[9];
    const float* bq       = (const float*)d_in[10];
    const float* Wk       = (const float*)d_in[11];
    // d_in[12] = bk (uniform over t -> cancels in softmax; unused)
    const float* Wv       = (const float*)d_in[13];
    const float* bv       = (const float*)d_in[14];
    const float* Wo       = (const float*)d_in[15];
    const float* bo       = (const float*)d_in[16];
    const float* Wg       = (const float*)d_in[17];
    const float* bg       = (const float*)d_in[18];
    float* out = (float*)d_out;
    float* ws  = (float*)d_ws;

    setup1_kernel<<<dim3(393), dim3(256), 0, stream>>>(Wk, Wv, Wo, Wg, bv, bo,
                                                       W_static, b_static, bg, E_var, ws);
    setup2_kernel<<<dim3(128), dim3(256), 0, stream>>>(Wk, ws);
    main_kernel<<<dim3(NB * NA / 2), dim3(512), 0, stream>>>(data, mask, W_embed, b_embed,
                                                             E_var, Wq, bq, ws);
    final_kernel<<<dim3(1), dim3(64), 0, stream>>>(statics, mask, ws, out);
}